// Round 3
// baseline (575.949 us; speedup 1.0000x reference)
//
#include <hip/hip_runtime.h>

#define S_LEN   2048
#define HID     4096
#define NHEADS  32
#define NKVH    8
#define HDIM    128
#define NQKV    6144          // NKV*(QPK+2)*HD = 8*6*128
#define ATT_SCALE (1.0f/128.0f)

typedef unsigned short u16;
typedef __attribute__((ext_vector_type(8))) __bf16 bf16x8;
typedef __attribute__((ext_vector_type(4))) float  f32x4;

__device__ __forceinline__ u16 f2bf(float f) {
    union { float f; unsigned u; } x; x.f = f;
    unsigned u = x.u;
    u += 0x7fffu + ((u >> 16) & 1u);   // round-to-nearest-even
    return (u16)(u >> 16);
}
__device__ __forceinline__ float bf2f(u16 v) {
    union { unsigned u; float f; } x; x.u = ((unsigned)v) << 16; return x.f;
}

// ---------------- fp32 -> bf16 conversion ----------------
__global__ __launch_bounds__(256) void cvt_bf16_kernel(const float* __restrict__ in,
                                                       u16* __restrict__ out, int n4) {
    int stride = gridDim.x * blockDim.x;
    for (int i = blockIdx.x * blockDim.x + threadIdx.x; i < n4; i += stride) {
        float4 v = *(const float4*)(in + (size_t)i * 4);
        ushort4 o = make_ushort4(f2bf(v.x), f2bf(v.y), f2bf(v.z), f2bf(v.w));
        *(ushort4*)(out + (size_t)i * 4) = o;
    }
}

// ---------------- 128x128 2-phase GEMM (proven ~800-900 TF) ----------------
#define BM 128
#define BN 128
#define BK 32

template <bool OUT_BF16>
__global__ __launch_bounds__(256) void gemm_bt_kernel(
    const u16* __restrict__ A,   // M x K  bf16
    const u16* __restrict__ B,   // N x K  bf16
    const float* __restrict__ bias, // N
    void* __restrict__ Cout,     // M x N  (fp32 or bf16)
    int M, int N, int K)
{
    __shared__ u16 Alds[2][BM][BK];
    __shared__ u16 Blds[2][BN][BK];

    const int tid  = threadIdx.x;
    const int wid  = tid >> 6;
    const int lane = tid & 63;
    const int ln   = lane & 15;
    const int quad = lane >> 4;
    const int wm   = (wid >> 1) * 64;
    const int wn   = (wid & 1) * 64;
    const int tileM = blockIdx.y * BM;
    const int tileN = blockIdx.x * BN;

    const int srow = lane >> 2;
    const int scol = ((lane & 3) ^ ((srow >> 1) & 3)) * 8;

    f32x4 acc[4][4];
    #pragma unroll
    for (int i = 0; i < 4; i++)
        #pragma unroll
        for (int j = 0; j < 4; j++) {
            f32x4 z = {0.f, 0.f, 0.f, 0.f};
            acc[i][j] = z;
        }

    auto stage = [&](int k, int buf) {
        const int k0 = k * BK;
        #pragma unroll
        for (int p = 0; p < 2; p++) {
            int r = p * 64 + wid * 16;
            const u16* ga = A + (size_t)(tileM + r + srow) * K + k0 + scol;
            const u16* gb = B + (size_t)(tileN + r + srow) * K + k0 + scol;
            __builtin_amdgcn_global_load_lds(
                (const __attribute__((address_space(1))) void*)ga,
                (__attribute__((address_space(3))) void*)&Alds[buf][r][0], 16, 0, 0);
            __builtin_amdgcn_global_load_lds(
                (const __attribute__((address_space(1))) void*)gb,
                (__attribute__((address_space(3))) void*)&Blds[buf][r][0], 16, 0, 0);
        }
    };

    const int nIter = K / BK;
    stage(0, 0);

    const int pc = (quad ^ ((ln >> 1) & 3)) * 8;

    for (int k = 0; k < nIter; k++) {
        const int buf = k & 1;
        __syncthreads();
        if (k + 1 < nIter) stage(k + 1, buf ^ 1);

        bf16x8 af[4], bfr[4];
        #pragma unroll
        for (int i = 0; i < 4; i++)
            af[i] = *(const bf16x8*)(&Alds[buf][wm + i * 16 + ln][pc]);
        #pragma unroll
        for (int j = 0; j < 4; j++)
            bfr[j] = *(const bf16x8*)(&Blds[buf][wn + j * 16 + ln][pc]);
        #pragma unroll
        for (int i = 0; i < 4; i++)
            #pragma unroll
            for (int j = 0; j < 4; j++)
                acc[i][j] = __builtin_amdgcn_mfma_f32_16x16x32_bf16(af[i], bfr[j], acc[i][j], 0, 0, 0);
    }

    #pragma unroll
    for (int i = 0; i < 4; i++) {
        #pragma unroll
        for (int j = 0; j < 4; j++) {
            int n = tileN + wn + j * 16 + ln;
            float bv = bias[n];
            #pragma unroll
            for (int r = 0; r < 4; r++) {
                int m = tileM + wm + i * 16 + quad * 4 + r;
                float v = acc[i][j][r] + bv;
                if (OUT_BF16)
                    ((u16*)Cout)[(size_t)m * N + n] = f2bf(v);
                else
                    ((float*)Cout)[(size_t)m * N + n] = v;
            }
        }
    }
}

// ---------------- 256x256 8-phase GEMM (T2+T3+T4+T5 template) ----------------
// 512 thr = 8 waves (2M x 4N). BK=64. LDS 128 KiB:
//   A[buf][half][128][64] @ elem 0, B[buf][half][128][64] @ elem 32768.
// Per-wave output 128x64, 4 quadrants Q(a,b). Phase computes one quadrant
// (16 MFMA) and stages one half-tile of K-tile t+1 into buf^1.
// Stage order A-h0,B-h0,A-h1,B-h1; counted waits vmcnt(6)@ph0, vmcnt(4)@ph1
// only (FIFO: 8 outstanding entering each tile; ph0's wait forces A-h0,B-h0
// of tile t; ph1's forces A-h1,B-h1). Never vmcnt(0) inside the loop (T4).
// CRITICAL: drain vmcnt(0) after the loop — in-flight LDS-DMA at s_endpgm
// corrupts the next workgroup's LDS (round-2 failure root cause).
// XOR swizzle col ^= ((row>>2)&1)<<4 elems (st_16x32-equivalent): linear
// gload_lds dest + inverse-swizzled global source + swizzled ds_read.
#define TBM 256
#define TBN 256
#define TBK 64

#define GFENCE() asm volatile("" ::: "memory")
#define GSBAR()  do { GFENCE(); __builtin_amdgcn_s_barrier(); GFENCE(); } while (0)

template <bool OUT_BF16>
__global__ __launch_bounds__(512, 2) void gemm_bt8_kernel(
    const u16* __restrict__ A,   // M x K  bf16
    const u16* __restrict__ B,   // N x K  bf16
    const float* __restrict__ bias,
    void* __restrict__ Cout,     // M x N
    int M, int N, int K)
{
    __shared__ u16 lds[65536];   // 128 KiB

    const int tid  = threadIdx.x;
    const int wid  = tid >> 6;        // 0..7
    const int lane = tid & 63;
    const int ln   = lane & 15;
    const int quad = lane >> 4;
    const int wr   = wid >> 2;        // 0..1 (M split)
    const int wc   = wid & 3;         // 0..3 (N split)
    const int tileM = blockIdx.y * TBM;
    const int tileN = blockIdx.x * TBN;

    f32x4 acc[2][2][4][2];            // [a][b][m][n]
    #pragma unroll
    for (int a = 0; a < 2; a++)
        #pragma unroll
        for (int b = 0; b < 2; b++)
            #pragma unroll
            for (int m = 0; m < 4; m++)
                #pragma unroll
                for (int n = 0; n < 2; n++) {
                    f32x4 z = {0.f, 0.f, 0.f, 0.f};
                    acc[a][b][m][n] = z;
                }

    const int srho  = lane >> 3;          // row within 8-row chunk
    const int scol0 = (lane & 7) << 3;    // 16B chunk -> elem col

    auto stage_half = [&](const u16* Mp, int tbase, int h, int kk, int bb, int isB) {
        const int ldsbase = isB * 32768 + (bb * 2 + h) * 8192;
        #pragma unroll
        for (int s = 0; s < 2; s++) {
            const int rho0 = s * 64 + wid * 8;            // wave-uniform
            const int rho  = rho0 + srho;
            const int col  = scol0 ^ (((rho >> 2) & 1) << 4);
            const u16* src = Mp + (size_t)(tbase + h * 128 + rho) * K + (size_t)kk * TBK + col;
            __builtin_amdgcn_global_load_lds(
                (const __attribute__((address_space(1))) void*)src,
                (__attribute__((address_space(3))) void*)&lds[ldsbase + rho0 * 64], 16, 0, 0);
        }
    };

    bf16x8 af[4][2];        // A frags for current a-strip  [m][ks]

#define READ_A(a_)                                                                  \
    do {                                                                            \
        _Pragma("unroll")                                                           \
        for (int m = 0; m < 4; m++) {                                               \
            const int ra = wr * 64 + m * 16 + ln;                                   \
            const int ab = (buf * 2 + (a_)) * 8192 + ra * 64;                       \
            const int sw = ((ra >> 2) & 1) << 4;                                    \
            af[m][0] = *(const bf16x8*)(&lds[ab + ((quad * 8) ^ sw)]);              \
            af[m][1] = *(const bf16x8*)(&lds[ab + ((32 + quad * 8) ^ sw)]);         \
        }                                                                           \
    } while (0)

#define READ_B(b_, bfr_)                                                            \
    do {                                                                            \
        _Pragma("unroll")                                                           \
        for (int n = 0; n < 2; n++) {                                               \
            const int rb = wc * 32 + n * 16 + ln;                                   \
            const int bbase = 32768 + (buf * 2 + (b_)) * 8192 + rb * 64;            \
            const int sw = ((rb >> 2) & 1) << 4;                                    \
            bfr_[n][0] = *(const bf16x8*)(&lds[bbase + ((quad * 8) ^ sw)]);         \
            bfr_[n][1] = *(const bf16x8*)(&lds[bbase + ((32 + quad * 8) ^ sw)]);    \
        }                                                                           \
    } while (0)

#define DO_MFMA(a_, b_, bfr_)                                                       \
    do {                                                                            \
        __builtin_amdgcn_s_setprio(1);                                              \
        _Pragma("unroll")                                                           \
        for (int m = 0; m < 4; m++)                                                 \
            _Pragma("unroll")                                                       \
            for (int n = 0; n < 2; n++) {                                           \
                acc[a_][b_][m][n] = __builtin_amdgcn_mfma_f32_16x16x32_bf16(        \
                    af[m][0], bfr_[n][0], acc[a_][b_][m][n], 0, 0, 0);              \
                acc[a_][b_][m][n] = __builtin_amdgcn_mfma_f32_16x16x32_bf16(        \
                    af[m][1], bfr_[n][1], acc[a_][b_][m][n], 0, 0, 0);              \
            }                                                                       \
        __builtin_amdgcn_s_setprio(0);                                              \
    } while (0)

    const int nIter = K / TBK;

    // prologue: stage K-tile 0 into buf0 (order matters for vmcnt counting)
    stage_half(A, tileM, 0, 0, 0, 0);
    stage_half(B, tileN, 0, 0, 0, 1);
    stage_half(A, tileM, 1, 0, 0, 0);
    stage_half(B, tileN, 1, 0, 0, 1);

    for (int t = 0; t < nIter; t++) {
        const int buf = t & 1;
        const int bn  = buf ^ 1;
        const int kn  = (t + 1 == nIter) ? 0 : t + 1;   // final-iter dummy keeps counts uniform

        // phase 0: Q(0,0) — needs A-h0,B-h0 of tile t
        stage_half(A, tileM, 0, kn, bn, 0);
        asm volatile("s_waitcnt vmcnt(6)" ::: "memory");
        GSBAR();
        {
            bf16x8 bfr[2][2];
            READ_A(0); READ_B(0, bfr);
            DO_MFMA(0, 0, bfr);
            GSBAR();

            // phase 1: Q(1,0) — A frags reused; stage B-h0 of t+1
            stage_half(B, tileN, 0, kn, bn, 1);
            asm volatile("s_waitcnt vmcnt(4)" ::: "memory");
            GSBAR();
            READ_A(1);                       // A-h1 forced by the vmcnt(4) above
            DO_MFMA(1, 0, bfr);
            GSBAR();
        }

        // phase 2: Q(1,1) — needs B-h1 (forced by ph1's vmcnt(4)); A-h1 frags live
        stage_half(A, tileM, 1, kn, bn, 0);
        GSBAR();
        {
            bf16x8 bfr[2][2];
            READ_B(1, bfr);
            DO_MFMA(1, 1, bfr);
            GSBAR();

            // phase 3: Q(0,1) — B-h1 frags reused
            stage_half(B, tileN, 1, kn, bn, 1);
            GSBAR();
            READ_A(0);
            DO_MFMA(0, 1, bfr);
            GSBAR();
        }
    }

    // CRITICAL drain: the last iteration's dummy stages are still in flight;
    // LDS-DMA landing after s_endpgm would corrupt the next workgroup's LDS.
    asm volatile("s_waitcnt vmcnt(0)" ::: "memory");

#undef READ_A
#undef READ_B
#undef DO_MFMA

    // epilogue
    #pragma unroll
    for (int a = 0; a < 2; a++)
        #pragma unroll
        for (int b = 0; b < 2; b++)
            #pragma unroll
            for (int n = 0; n < 2; n++) {
                #pragma unroll
                for (int m = 0; m < 4; m++) {
                    const int col = tileN + b * 128 + wc * 32 + n * 16 + ln;
                    const float bv = bias[col];
                    #pragma unroll
                    for (int r = 0; r < 4; r++) {
                        const int row = tileM + a * 128 + wr * 64 + m * 16 + quad * 4 + r;
                        float v = acc[a][b][m][n][r] + bv;
                        if (OUT_BF16)
                            ((u16*)Cout)[(size_t)row * N + col] = f2bf(v);
                        else
                            ((float*)Cout)[(size_t)row * N + col] = v;
                    }
                }
            }
}

// ---------------- RoPE + split qkv (bf16 in, bf16 out) ----------------
__global__ __launch_bounds__(128) void rope_split_kernel(
    const u16* __restrict__ qkv, const int* __restrict__ positions,
    u16* __restrict__ qb_o, u16* __restrict__ kb_o, u16* __restrict__ vb_o)
{
    const int d   = threadIdx.x;     // 0..127
    const int pos = blockIdx.x;      // 0..S-1
    const int hy  = blockIdx.y;      // 0..47
    const float p = (float)positions[pos];

    if (hy >= NHEADS + NKVH) {               // v copy
        int kv = hy - NHEADS - NKVH;
        const u16* src = qkv + (size_t)pos * NQKV + (kv * 6 + 5) * HDIM;
        vb_o[((size_t)kv * S_LEN + pos) * HDIM + d] = src[d];
        return;
    }
    const u16* src;
    u16* dst;
    if (hy < NHEADS) {                        // q head
        int kv = hy >> 2, qi = hy & 3;
        src = qkv + (size_t)pos * NQKV + (kv * 6 + qi) * HDIM;
        dst = qb_o + ((size_t)hy * S_LEN + pos) * HDIM;
    } else {                                  // k head
        int kv = hy - NHEADS;
        src = qkv + (size_t)pos * NQKV + (kv * 6 + 4) * HDIM;
        dst = kb_o + ((size_t)kv * S_LEN + pos) * HDIM;
    }
    int d2 = d & 63;
    float inv = expf(-(float)d2 * (13.815510557964274f / 64.0f)); // 1e6^(-d2/64)
    float fr = p * inv;
    float s, c;
    sincosf(fr, &s, &c);
    float x1 = bf2f(src[d2]);
    float x2 = bf2f(src[d2 + 64]);
    float o = (d < 64) ? (x1 * c - x2 * s) : (x2 * c + x1 * s);
    dst[d] = f2bf(o);
}

// ---------------- blocksparse flash attention ----------------
// grid (S/64, NH); block 256 (4 waves). Wave w owns query rows w*16..w*16+15.
// Q in regs; K via gload_lds + XOR swizzle; Vt/P swizzled; 2 barriers/tile;
// LDS 40960 B -> 4 blocks/CU; qb reversed; setprio on MFMA clusters.
__global__ __launch_bounds__(256, 4) void attn_bs_kernel(
    const u16* __restrict__ Q,   // (NH, S, HD) bf16
    const u16* __restrict__ K,   // (NKV, S, HD)
    const u16* __restrict__ V,   // (NKV, S, HD)
    u16* __restrict__ O)         // (S, NH*HD) bf16
{
    __shared__ u16 Ks[64 * 128];      // 16 KB, swizzled
    __shared__ u16 Vt[128 * 64];      // 16 KB, V^T, swizzled
    __shared__ u16 Ps[4][16 * 64];    // 8 KB, per-wave P, swizzled

    const int qb = (int)gridDim.x - 1 - (int)blockIdx.x;   // heavy blocks first
    const int h  = blockIdx.y;
    const int kv = h >> 2;
    const int tid  = threadIdx.x;
    const int w    = tid >> 6;
    const int lane = tid & 63;
    const int ln   = lane & 15;
    const int quad = lane >> 4;

    bf16x8 aq[4];
    {
        const u16* Qg = Q + ((size_t)h * S_LEN + qb * 64 + w * 16 + ln) * HDIM + quad * 8;
        #pragma unroll
        for (int ks = 0; ks < 4; ks++)
            aq[ks] = *(const bf16x8*)(Qg + ks * 32);
    }

    f32x4 oacc[8];
    #pragma unroll
    for (int n = 0; n < 8; n++) { f32x4 z = {0.f,0.f,0.f,0.f}; oacc[n] = z; }
    float mrow[4] = {-1e30f, -1e30f, -1e30f, -1e30f};
    float lrow[4] = {0.f, 0.f, 0.f, 0.f};

    for (int kb = 0; kb <= qb; kb++) {
        bool sel = (qb - kb < 16) || (((kb + h + 1) & 7) == 0);
        if (!sel) continue;

        __syncthreads();   // previous iteration's Ks/Vt reads complete

        const u16* Kg = K + ((size_t)kv * S_LEN + kb * 64) * HDIM;
        const u16* Vg = V + ((size_t)kv * S_LEN + kb * 64) * HDIM;

        #pragma unroll
        for (int p = 0; p < 4; p++) {
            int r0  = w * 16 + p * 4;
            int row = r0 + (lane >> 4);
            const u16* src = Kg + (size_t)row * HDIM + (((lane & 15) ^ (row & 7)) << 3);
            __builtin_amdgcn_global_load_lds(
                (const __attribute__((address_space(1))) void*)src,
                (__attribute__((address_space(3))) void*)&Ks[r0 * 128], 16, 0, 0);
        }

        {
            int dbase = w * 32;
            #pragma unroll
            for (int p = 0; p < 4; p++) {
                int d0 = dbase + p * 8;
                uint4 vv = *(const uint4*)(Vg + (size_t)lane * HDIM + d0);
                const u16* pvv = (const u16*)&vv;
                #pragma unroll
                for (int jj = 0; jj < 8; jj++) {
                    int d = d0 + jj;
                    Vt[d * 64 + ((((lane >> 3)) ^ (d & 7)) << 3) + (lane & 7)] = pvv[jj];
                }
            }
        }
        __syncthreads();

        f32x4 sacc[4];
        #pragma unroll
        for (int jj = 0; jj < 4; jj++) { f32x4 z = {0.f,0.f,0.f,0.f}; sacc[jj] = z; }
        __builtin_amdgcn_s_setprio(1);
        #pragma unroll
        for (int ks = 0; ks < 4; ks++) {
            #pragma unroll
            for (int jj = 0; jj < 4; jj++) {
                bf16x8 bk = *(const bf16x8*)(
                    &Ks[(jj * 16 + ln) * 128 + (((ks * 4 + quad) ^ (ln & 7)) << 3)]);
                sacc[jj] = __builtin_amdgcn_mfma_f32_16x16x32_bf16(aq[ks], bk, sacc[jj], 0, 0, 0);
            }
        }
        __builtin_amdgcn_s_setprio(0);

        #pragma unroll
        for (int r = 0; r < 4; r++) {
            float pv[4];
            float mx = -1e30f;
            const int qrow = w * 16 + quad * 4 + r;
            #pragma unroll
            for (int jj = 0; jj < 4; jj++) {
                float s = sacc[jj][r] * ATT_SCALE;
                if (kb == qb && (jj * 16 + ln) > qrow) s = -1e30f;
                pv[jj] = s;
                mx = fmaxf(mx, s);
            }
            #pragma unroll
            for (int off = 1; off < 16; off <<= 1)
                mx = fmaxf(mx, __shfl_xor(mx, off, 64));
            float mnew  = fmaxf(mrow[r], mx);
            float alpha = __expf(mrow[r] - mnew);
            float sum = 0.f;
            #pragma unroll
            for (int jj = 0; jj < 4; jj++) {
                float pe = __expf(pv[jj] - mnew);
                pv[jj] = pe;
                sum += pe;
            }
            #pragma unroll
            for (int off = 1; off < 16; off <<= 1)
                sum += __shfl_xor(sum, off, 64);
            lrow[r] = lrow[r] * alpha + sum;
            mrow[r] = mnew;
            #pragma unroll
            for (int n = 0; n < 8; n++) oacc[n][r] *= alpha;
            const int prow = quad * 4 + r;
            #pragma unroll
            for (int jj = 0; jj < 4; jj++)
                Ps[w][prow * 64 + (((jj * 2 + (ln >> 3)) ^ (prow & 7)) << 3) + (ln & 7)]
                    = f2bf(pv[jj]);
        }
        // no barrier: Ps[w] is written and read only by wave w (in-order DS pipe)

        __builtin_amdgcn_s_setprio(1);
        #pragma unroll
        for (int kk = 0; kk < 2; kk++) {
            bf16x8 ap = *(const bf16x8*)(
                &Ps[w][ln * 64 + (((kk * 4 + quad) ^ (ln & 7)) << 3)]);
            #pragma unroll
            for (int n = 0; n < 8; n++) {
                bf16x8 bv = *(const bf16x8*)(
                    &Vt[(n * 16 + ln) * 64 + (((kk * 4 + quad) ^ (ln & 7)) << 3)]);
                oacc[n] = __builtin_amdgcn_mfma_f32_16x16x32_bf16(ap, bv, oacc[n], 0, 0, 0);
            }
        }
        __builtin_amdgcn_s_setprio(0);
    }

    #pragma unroll
    for (int n = 0; n < 8; n++) {
        #pragma unroll
        for (int r = 0; r < 4; r++) {
            int row = w * 16 + quad * 4 + r;
            int pos = qb * 64 + row;
            float o = oacc[n][r] / lrow[r];
            O[(size_t)pos * (NHEADS * HDIM) + h * HDIM + n * 16 + ln] = f2bf(o);
        }
    }
}

// ---------------- launch ----------------
extern "C" void kernel_launch(void* const* d_in, const int* in_sizes, int n_in,
                              void* d_out, int out_size, void* d_ws, size_t ws_size,
                              hipStream_t stream) {
    const int*   positions = (const int*)d_in[0];
    const float* hidden    = (const float*)d_in[1];
    const float* w_qkv     = (const float*)d_in[2];
    const float* b_qkv     = (const float*)d_in[3];
    const float* w_dense   = (const float*)d_in[4];
    const float* b_dense   = (const float*)d_in[5];
    float* out = (float*)d_out;

    char* ws = (char*)d_ws;
    u16* ws_h    = (u16*)(ws);                    // 2048*4096*2   = 16,777,216
    u16* ws_wqkv = (u16*)(ws + 16777216);         // 6144*4096*2  = 50,331,648
    u16* ws_wd   = (u16*)(ws + 67108864);         // 4096*4096*2  = 33,554,432
    u16* ws_qkv  = (u16*)(ws + 100663296);        // 2048*6144*2  = 25,165,824 (bf16)
    u16* ws_q    = (u16*)(ws + 125829120);        // 32*2048*128*2= 16,777,216
    u16* ws_k    = (u16*)(ws + 142606336);        // 8*2048*128*2 =  4,194,304
    u16* ws_v    = (u16*)(ws + 146800640);        //               =  4,194,304
    u16* ws_attn = (u16*)(ws + 150994944);        // 2048*4096*2  = 16,777,216

    cvt_bf16_kernel<<<1024, 256, 0, stream>>>(hidden,  ws_h,    (S_LEN * HID) / 4);
    cvt_bf16_kernel<<<2048, 256, 0, stream>>>(w_qkv,   ws_wqkv, (NQKV * HID) / 4);
    cvt_bf16_kernel<<<2048, 256, 0, stream>>>(w_dense, ws_wd,   (HID * HID) / 4);

    // QKV GEMM: 256^2 8-phase (grid 24x8 = 192 blocks)
    gemm_bt8_kernel<true><<<dim3(NQKV / TBN, S_LEN / TBM), 512, 0, stream>>>(
        ws_h, ws_wqkv, b_qkv, ws_qkv, S_LEN, NQKV, HID);

    rope_split_kernel<<<dim3(S_LEN, NHEADS + 2 * NKVH), 128, 0, stream>>>(
        ws_qkv, positions, ws_q, ws_k, ws_v);

    attn_bs_kernel<<<dim3(S_LEN / 64, NHEADS), 256, 0, stream>>>(ws_q, ws_k, ws_v, ws_attn);

    // dense GEMM: keep 128^2 kernel this round (isolates the 8-phase measurement)
    gemm_bt_kernel<false><<<dim3(HID / BN, S_LEN / BM), 256, 0, stream>>>(
        ws_attn, ws_wd, b_dense, out, S_LEN, HID, HID);
}

// Round 4
// 562.514 us; speedup vs baseline: 1.0239x; 1.0239x over previous
//
#include <hip/hip_runtime.h>

#define S_LEN   2048
#define HID     4096
#define NHEADS  32
#define NKVH    8
#define HDIM    128
#define NQKV    6144          // NKV*(QPK+2)*HD = 8*6*128
#define ATT_SCALE (1.0f/128.0f)

typedef unsigned short u16;
typedef __attribute__((ext_vector_type(8))) __bf16 bf16x8;
typedef __attribute__((ext_vector_type(4))) float  f32x4;

__device__ __forceinline__ u16 f2bf(float f) {
    union { float f; unsigned u; } x; x.f = f;
    unsigned u = x.u;
    u += 0x7fffu + ((u >> 16) & 1u);   // round-to-nearest-even
    return (u16)(u >> 16);
}
__device__ __forceinline__ float bf2f(u16 v) {
    union { unsigned u; float f; } x; x.u = ((unsigned)v) << 16; return x.f;
}

// ---------------- fp32 -> bf16 conversion ----------------
__global__ __launch_bounds__(256) void cvt_bf16_kernel(const float* __restrict__ in,
                                                       u16* __restrict__ out, int n4) {
    int stride = gridDim.x * blockDim.x;
    for (int i = blockIdx.x * blockDim.x + threadIdx.x; i < n4; i += stride) {
        float4 v = *(const float4*)(in + (size_t)i * 4);
        ushort4 o = make_ushort4(f2bf(v.x), f2bf(v.y), f2bf(v.z), f2bf(v.w));
        *(ushort4*)(out + (size_t)i * 4) = o;
    }
}

// ---------------- 128x128 2-phase GEMM (proven ~800-900 TF) ----------------
#define BM 128
#define BN 128
#define BK 32

template <bool OUT_BF16>
__global__ __launch_bounds__(256) void gemm_bt_kernel(
    const u16* __restrict__ A,   // M x K  bf16
    const u16* __restrict__ B,   // N x K  bf16
    const float* __restrict__ bias, // N
    void* __restrict__ Cout,     // M x N  (fp32 or bf16)
    int M, int N, int K)
{
    __shared__ u16 Alds[2][BM][BK];
    __shared__ u16 Blds[2][BN][BK];

    const int tid  = threadIdx.x;
    const int wid  = tid >> 6;
    const int lane = tid & 63;
    const int ln   = lane & 15;
    const int quad = lane >> 4;
    const int wm   = (wid >> 1) * 64;
    const int wn   = (wid & 1) * 64;
    const int tileM = blockIdx.y * BM;
    const int tileN = blockIdx.x * BN;

    const int srow = lane >> 2;
    const int scol = ((lane & 3) ^ ((srow >> 1) & 3)) * 8;

    f32x4 acc[4][4];
    #pragma unroll
    for (int i = 0; i < 4; i++)
        #pragma unroll
        for (int j = 0; j < 4; j++) {
            f32x4 z = {0.f, 0.f, 0.f, 0.f};
            acc[i][j] = z;
        }

    auto stage = [&](int k, int buf) {
        const int k0 = k * BK;
        #pragma unroll
        for (int p = 0; p < 2; p++) {
            int r = p * 64 + wid * 16;
            const u16* ga = A + (size_t)(tileM + r + srow) * K + k0 + scol;
            const u16* gb = B + (size_t)(tileN + r + srow) * K + k0 + scol;
            __builtin_amdgcn_global_load_lds(
                (const __attribute__((address_space(1))) void*)ga,
                (__attribute__((address_space(3))) void*)&Alds[buf][r][0], 16, 0, 0);
            __builtin_amdgcn_global_load_lds(
                (const __attribute__((address_space(1))) void*)gb,
                (__attribute__((address_space(3))) void*)&Blds[buf][r][0], 16, 0, 0);
        }
    };

    const int nIter = K / BK;
    stage(0, 0);

    const int pc = (quad ^ ((ln >> 1) & 3)) * 8;

    for (int k = 0; k < nIter; k++) {
        const int buf = k & 1;
        __syncthreads();
        if (k + 1 < nIter) stage(k + 1, buf ^ 1);

        bf16x8 af[4], bfr[4];
        #pragma unroll
        for (int i = 0; i < 4; i++)
            af[i] = *(const bf16x8*)(&Alds[buf][wm + i * 16 + ln][pc]);
        #pragma unroll
        for (int j = 0; j < 4; j++)
            bfr[j] = *(const bf16x8*)(&Blds[buf][wn + j * 16 + ln][pc]);
        #pragma unroll
        for (int i = 0; i < 4; i++)
            #pragma unroll
            for (int j = 0; j < 4; j++)
                acc[i][j] = __builtin_amdgcn_mfma_f32_16x16x32_bf16(af[i], bfr[j], acc[i][j], 0, 0, 0);
    }

    #pragma unroll
    for (int i = 0; i < 4; i++) {
        #pragma unroll
        for (int j = 0; j < 4; j++) {
            int n = tileN + wn + j * 16 + ln;
            float bv = bias[n];
            #pragma unroll
            for (int r = 0; r < 4; r++) {
                int m = tileM + wm + i * 16 + quad * 4 + r;
                float v = acc[i][j][r] + bv;
                if (OUT_BF16)
                    ((u16*)Cout)[(size_t)m * N + n] = f2bf(v);
                else
                    ((float*)Cout)[(size_t)m * N + n] = v;
            }
        }
    }
}

// ---------------- 256x256 8-phase GEMM (T2+T3+T4+T5 template) ----------------
// 512 thr = 8 waves (2M x 4N). BK=64. LDS 128 KiB:
//   A[buf][half][128][64] @ elem 0, B[buf][half][128][64] @ elem 32768.
// Per-wave output 128x64, 4 quadrants Q(a,b). Phase computes one quadrant
// (16 MFMA) and stages one half-tile of K-tile t+1 into buf^1.
// Counted waits vmcnt(6)@ph0, vmcnt(4)@ph1 only; never vmcnt(0) in-loop (T4).
// Drain vmcnt(0) after the loop (in-flight LDS-DMA at s_endpgm corrupts the
// next workgroup's LDS — round-2 failure root cause).
// T2 swizzle (FIXED round 4): FULL 3-bit XOR — physical 16B chunk =
// logical ^ (row&7). Round-3's 1-bit swizzle left 8-way ds_read_b128
// conflicts (12.6M cycles): 16 lanes read 16 consecutive rows (stride 128B
// = bank period) at one logical chunk -> only 2 phys slots. 3-bit spreads
// them over 8 slots = all 32 banks, 2 lanes/slot = free (m136).
// Both-sides involution (rule #21): linear gload_lds dest + source fetches
// chunk (lane&7)^ (row&7); read XORs chunk with (row&7).
#define TBM 256
#define TBN 256
#define TBK 64

#define GFENCE() asm volatile("" ::: "memory")
#define GSBAR()  do { GFENCE(); __builtin_amdgcn_s_barrier(); GFENCE(); } while (0)

template <bool OUT_BF16>
__global__ __launch_bounds__(512, 2) void gemm_bt8_kernel(
    const u16* __restrict__ A,   // M x K  bf16
    const u16* __restrict__ B,   // N x K  bf16
    const float* __restrict__ bias,
    void* __restrict__ Cout,     // M x N
    int M, int N, int K)
{
    __shared__ u16 lds[65536];   // 128 KiB

    const int tid  = threadIdx.x;
    const int wid  = tid >> 6;        // 0..7
    const int lane = tid & 63;
    const int ln   = lane & 15;
    const int quad = lane >> 4;
    const int wr   = wid >> 2;        // 0..1 (M split)
    const int wc   = wid & 3;         // 0..3 (N split)
    const int tileM = blockIdx.y * TBM;
    const int tileN = blockIdx.x * TBN;

    f32x4 acc[2][2][4][2];            // [a][b][m][n]
    #pragma unroll
    for (int a = 0; a < 2; a++)
        #pragma unroll
        for (int b = 0; b < 2; b++)
            #pragma unroll
            for (int m = 0; m < 4; m++)
                #pragma unroll
                for (int n = 0; n < 2; n++) {
                    f32x4 z = {0.f, 0.f, 0.f, 0.f};
                    acc[a][b][m][n] = z;
                }

    const int srho = lane >> 3;                       // row within 8-row chunk (0..7)
    // source chunk pre-swizzle: row base rho0 is ≡0 (mod 8), so row&7 == srho.
    const int scol = (((lane & 7) ^ srho) << 3);      // elem col of 16B chunk

    auto stage_half = [&](const u16* Mp, int tbase, int h, int kk, int bb, int isB) {
        const int ldsbase = isB * 32768 + (bb * 2 + h) * 8192;
        #pragma unroll
        for (int s = 0; s < 2; s++) {
            const int rho0 = s * 64 + wid * 8;            // wave-uniform, ≡0 mod 8
            const int rho  = rho0 + srho;
            const u16* src = Mp + (size_t)(tbase + h * 128 + rho) * K + (size_t)kk * TBK + scol;
            __builtin_amdgcn_global_load_lds(
                (const __attribute__((address_space(1))) void*)src,
                (__attribute__((address_space(3))) void*)&lds[ldsbase + rho0 * 64], 16, 0, 0);
        }
    };

    bf16x8 af[4][2];        // A frags for current a-strip  [m][ks]

#define READ_A(a_)                                                                  \
    do {                                                                            \
        _Pragma("unroll")                                                           \
        for (int m = 0; m < 4; m++) {                                               \
            const int ra = wr * 64 + m * 16 + ln;                                   \
            const int ab = (buf * 2 + (a_)) * 8192 + ra * 64;                       \
            const int rx = ra & 7;                                                  \
            af[m][0] = *(const bf16x8*)(&lds[ab + ((quad ^ rx) << 3)]);             \
            af[m][1] = *(const bf16x8*)(&lds[ab + (((4 + quad) ^ rx) << 3)]);       \
        }                                                                           \
    } while (0)

#define READ_B(b_, bfr_)                                                            \
    do {                                                                            \
        _Pragma("unroll")                                                           \
        for (int n = 0; n < 2; n++) {                                               \
            const int rb = wc * 32 + n * 16 + ln;                                   \
            const int bbase = 32768 + (buf * 2 + (b_)) * 8192 + rb * 64;            \
            const int rx = rb & 7;                                                  \
            bfr_[n][0] = *(const bf16x8*)(&lds[bbase + ((quad ^ rx) << 3)]);        \
            bfr_[n][1] = *(const bf16x8*)(&lds[bbase + (((4 + quad) ^ rx) << 3)]);  \
        }                                                                           \
    } while (0)

#define DO_MFMA(a_, b_, bfr_)                                                       \
    do {                                                                            \
        __builtin_amdgcn_s_setprio(1);                                              \
        _Pragma("unroll")                                                           \
        for (int m = 0; m < 4; m++)                                                 \
            _Pragma("unroll")                                                       \
            for (int n = 0; n < 2; n++) {                                           \
                acc[a_][b_][m][n] = __builtin_amdgcn_mfma_f32_16x16x32_bf16(        \
                    af[m][0], bfr_[n][0], acc[a_][b_][m][n], 0, 0, 0);              \
                acc[a_][b_][m][n] = __builtin_amdgcn_mfma_f32_16x16x32_bf16(        \
                    af[m][1], bfr_[n][1], acc[a_][b_][m][n], 0, 0, 0);              \
            }                                                                       \
        __builtin_amdgcn_s_setprio(0);                                              \
    } while (0)

    const int nIter = K / TBK;

    // prologue: stage K-tile 0 into buf0 (order matters for vmcnt counting)
    stage_half(A, tileM, 0, 0, 0, 0);
    stage_half(B, tileN, 0, 0, 0, 1);
    stage_half(A, tileM, 1, 0, 0, 0);
    stage_half(B, tileN, 1, 0, 0, 1);

    for (int t = 0; t < nIter; t++) {
        const int buf = t & 1;
        const int bn  = buf ^ 1;
        const int kn  = (t + 1 == nIter) ? 0 : t + 1;   // final-iter dummy keeps counts uniform

        // phase 0: Q(0,0) — needs A-h0,B-h0 of tile t
        stage_half(A, tileM, 0, kn, bn, 0);
        asm volatile("s_waitcnt vmcnt(6)" ::: "memory");
        GSBAR();
        {
            bf16x8 bfr[2][2];
            READ_A(0); READ_B(0, bfr);
            DO_MFMA(0, 0, bfr);
            GSBAR();

            // phase 1: Q(1,0) — A frags reused; stage B-h0 of t+1
            stage_half(B, tileN, 0, kn, bn, 1);
            asm volatile("s_waitcnt vmcnt(4)" ::: "memory");
            GSBAR();
            READ_A(1);                       // A-h1 forced by the vmcnt(4) above
            DO_MFMA(1, 0, bfr);
            GSBAR();
        }

        // phase 2: Q(1,1) — needs B-h1 (forced by ph1's vmcnt(4)); A-h1 frags live
        stage_half(A, tileM, 1, kn, bn, 0);
        GSBAR();
        {
            bf16x8 bfr[2][2];
            READ_B(1, bfr);
            DO_MFMA(1, 1, bfr);
            GSBAR();

            // phase 3: Q(0,1) — B-h1 frags reused
            stage_half(B, tileN, 1, kn, bn, 1);
            GSBAR();
            READ_A(0);
            DO_MFMA(0, 1, bfr);
            GSBAR();
        }
    }

    // CRITICAL drain: the last iteration's dummy stages are still in flight;
    // LDS-DMA landing after s_endpgm would corrupt the next workgroup's LDS.
    asm volatile("s_waitcnt vmcnt(0)" ::: "memory");

#undef READ_A
#undef READ_B
#undef DO_MFMA

    // epilogue
    #pragma unroll
    for (int a = 0; a < 2; a++)
        #pragma unroll
        for (int b = 0; b < 2; b++)
            #pragma unroll
            for (int n = 0; n < 2; n++) {
                #pragma unroll
                for (int m = 0; m < 4; m++) {
                    const int col = tileN + b * 128 + wc * 32 + n * 16 + ln;
                    const float bv = bias[col];
                    #pragma unroll
                    for (int r = 0; r < 4; r++) {
                        const int row = tileM + a * 128 + wr * 64 + m * 16 + quad * 4 + r;
                        float v = acc[a][b][m][n][r] + bv;
                        if (OUT_BF16)
                            ((u16*)Cout)[(size_t)row * N + col] = f2bf(v);
                        else
                            ((float*)Cout)[(size_t)row * N + col] = v;
                    }
                }
            }
}

// ---------------- RoPE + split qkv (bf16 in, bf16 out) ----------------
__global__ __launch_bounds__(128) void rope_split_kernel(
    const u16* __restrict__ qkv, const int* __restrict__ positions,
    u16* __restrict__ qb_o, u16* __restrict__ kb_o, u16* __restrict__ vb_o)
{
    const int d   = threadIdx.x;     // 0..127
    const int pos = blockIdx.x;      // 0..S-1
    const int hy  = blockIdx.y;      // 0..47
    const float p = (float)positions[pos];

    if (hy >= NHEADS + NKVH) {               // v copy
        int kv = hy - NHEADS - NKVH;
        const u16* src = qkv + (size_t)pos * NQKV + (kv * 6 + 5) * HDIM;
        vb_o[((size_t)kv * S_LEN + pos) * HDIM + d] = src[d];
        return;
    }
    const u16* src;
    u16* dst;
    if (hy < NHEADS) {                        // q head
        int kv = hy >> 2, qi = hy & 3;
        src = qkv + (size_t)pos * NQKV + (kv * 6 + qi) * HDIM;
        dst = qb_o + ((size_t)hy * S_LEN + pos) * HDIM;
    } else {                                  // k head
        int kv = hy - NHEADS;
        src = qkv + (size_t)pos * NQKV + (kv * 6 + 4) * HDIM;
        dst = kb_o + ((size_t)kv * S_LEN + pos) * HDIM;
    }
    int d2 = d & 63;
    float inv = expf(-(float)d2 * (13.815510557964274f / 64.0f)); // 1e6^(-d2/64)
    float fr = p * inv;
    float s, c;
    sincosf(fr, &s, &c);
    float x1 = bf2f(src[d2]);
    float x2 = bf2f(src[d2 + 64]);
    float o = (d < 64) ? (x1 * c - x2 * s) : (x2 * c + x1 * s);
    dst[d] = f2bf(o);
}

// ---------------- blocksparse flash attention ----------------
// grid (S/64, NH); block 256 (4 waves). Wave w owns query rows w*16..w*16+15.
// Q in regs; K via gload_lds + XOR swizzle; Vt/P swizzled; 2 barriers/tile;
// LDS 40960 B -> 4 blocks/CU; qb reversed; setprio on MFMA clusters.
__global__ __launch_bounds__(256, 4) void attn_bs_kernel(
    const u16* __restrict__ Q,   // (NH, S, HD) bf16
    const u16* __restrict__ K,   // (NKV, S, HD)
    const u16* __restrict__ V,   // (NKV, S, HD)
    u16* __restrict__ O)         // (S, NH*HD) bf16
{
    __shared__ u16 Ks[64 * 128];      // 16 KB, swizzled
    __shared__ u16 Vt[128 * 64];      // 16 KB, V^T, swizzled
    __shared__ u16 Ps[4][16 * 64];    // 8 KB, per-wave P, swizzled

    const int qb = (int)gridDim.x - 1 - (int)blockIdx.x;   // heavy blocks first
    const int h  = blockIdx.y;
    const int kv = h >> 2;
    const int tid  = threadIdx.x;
    const int w    = tid >> 6;
    const int lane = tid & 63;
    const int ln   = lane & 15;
    const int quad = lane >> 4;

    bf16x8 aq[4];
    {
        const u16* Qg = Q + ((size_t)h * S_LEN + qb * 64 + w * 16 + ln) * HDIM + quad * 8;
        #pragma unroll
        for (int ks = 0; ks < 4; ks++)
            aq[ks] = *(const bf16x8*)(Qg + ks * 32);
    }

    f32x4 oacc[8];
    #pragma unroll
    for (int n = 0; n < 8; n++) { f32x4 z = {0.f,0.f,0.f,0.f}; oacc[n] = z; }
    float mrow[4] = {-1e30f, -1e30f, -1e30f, -1e30f};
    float lrow[4] = {0.f, 0.f, 0.f, 0.f};

    for (int kb = 0; kb <= qb; kb++) {
        bool sel = (qb - kb < 16) || (((kb + h + 1) & 7) == 0);
        if (!sel) continue;

        __syncthreads();   // previous iteration's Ks/Vt reads complete

        const u16* Kg = K + ((size_t)kv * S_LEN + kb * 64) * HDIM;
        const u16* Vg = V + ((size_t)kv * S_LEN + kb * 64) * HDIM;

        #pragma unroll
        for (int p = 0; p < 4; p++) {
            int r0  = w * 16 + p * 4;
            int row = r0 + (lane >> 4);
            const u16* src = Kg + (size_t)row * HDIM + (((lane & 15) ^ (row & 7)) << 3);
            __builtin_amdgcn_global_load_lds(
                (const __attribute__((address_space(1))) void*)src,
                (__attribute__((address_space(3))) void*)&Ks[r0 * 128], 16, 0, 0);
        }

        {
            int dbase = w * 32;
            #pragma unroll
            for (int p = 0; p < 4; p++) {
                int d0 = dbase + p * 8;
                uint4 vv = *(const uint4*)(Vg + (size_t)lane * HDIM + d0);
                const u16* pvv = (const u16*)&vv;
                #pragma unroll
                for (int jj = 0; jj < 8; jj++) {
                    int d = d0 + jj;
                    Vt[d * 64 + ((((lane >> 3)) ^ (d & 7)) << 3) + (lane & 7)] = pvv[jj];
                }
            }
        }
        __syncthreads();

        f32x4 sacc[4];
        #pragma unroll
        for (int jj = 0; jj < 4; jj++) { f32x4 z = {0.f,0.f,0.f,0.f}; sacc[jj] = z; }
        __builtin_amdgcn_s_setprio(1);
        #pragma unroll
        for (int ks = 0; ks < 4; ks++) {
            #pragma unroll
            for (int jj = 0; jj < 4; jj++) {
                bf16x8 bk = *(const bf16x8*)(
                    &Ks[(jj * 16 + ln) * 128 + (((ks * 4 + quad) ^ (ln & 7)) << 3)]);
                sacc[jj] = __builtin_amdgcn_mfma_f32_16x16x32_bf16(aq[ks], bk, sacc[jj], 0, 0, 0);
            }
        }
        __builtin_amdgcn_s_setprio(0);

        #pragma unroll
        for (int r = 0; r < 4; r++) {
            float pv[4];
            float mx = -1e30f;
            const int qrow = w * 16 + quad * 4 + r;
            #pragma unroll
            for (int jj = 0; jj < 4; jj++) {
                float s = sacc[jj][r] * ATT_SCALE;
                if (kb == qb && (jj * 16 + ln) > qrow) s = -1e30f;
                pv[jj] = s;
                mx = fmaxf(mx, s);
            }
            #pragma unroll
            for (int off = 1; off < 16; off <<= 1)
                mx = fmaxf(mx, __shfl_xor(mx, off, 64));
            float mnew  = fmaxf(mrow[r], mx);
            float alpha = __expf(mrow[r] - mnew);
            float sum = 0.f;
            #pragma unroll
            for (int jj = 0; jj < 4; jj++) {
                float pe = __expf(pv[jj] - mnew);
                pv[jj] = pe;
                sum += pe;
            }
            #pragma unroll
            for (int off = 1; off < 16; off <<= 1)
                sum += __shfl_xor(sum, off, 64);
            lrow[r] = lrow[r] * alpha + sum;
            mrow[r] = mnew;
            #pragma unroll
            for (int n = 0; n < 8; n++) oacc[n][r] *= alpha;
            const int prow = quad * 4 + r;
            #pragma unroll
            for (int jj = 0; jj < 4; jj++)
                Ps[w][prow * 64 + (((jj * 2 + (ln >> 3)) ^ (prow & 7)) << 3) + (ln & 7)]
                    = f2bf(pv[jj]);
        }
        // no barrier: Ps[w] is written and read only by wave w (in-order DS pipe)

        __builtin_amdgcn_s_setprio(1);
        #pragma unroll
        for (int kk = 0; kk < 2; kk++) {
            bf16x8 ap = *(const bf16x8*)(
                &Ps[w][ln * 64 + (((kk * 4 + quad) ^ (ln & 7)) << 3)]);
            #pragma unroll
            for (int n = 0; n < 8; n++) {
                bf16x8 bv = *(const bf16x8*)(
                    &Vt[(n * 16 + ln) * 64 + (((kk * 4 + quad) ^ (ln & 7)) << 3)]);
                oacc[n] = __builtin_amdgcn_mfma_f32_16x16x32_bf16(ap, bv, oacc[n], 0, 0, 0);
            }
        }
        __builtin_amdgcn_s_setprio(0);
    }

    #pragma unroll
    for (int n = 0; n < 8; n++) {
        #pragma unroll
        for (int r = 0; r < 4; r++) {
            int row = w * 16 + quad * 4 + r;
            int pos = qb * 64 + row;
            float o = oacc[n][r] / lrow[r];
            O[(size_t)pos * (NHEADS * HDIM) + h * HDIM + n * 16 + ln] = f2bf(o);
        }
    }
}

// ---------------- launch ----------------
extern "C" void kernel_launch(void* const* d_in, const int* in_sizes, int n_in,
                              void* d_out, int out_size, void* d_ws, size_t ws_size,
                              hipStream_t stream) {
    const int*   positions = (const int*)d_in[0];
    const float* hidden    = (const float*)d_in[1];
    const float* w_qkv     = (const float*)d_in[2];
    const float* b_qkv     = (const float*)d_in[3];
    const float* w_dense   = (const float*)d_in[4];
    const float* b_dense   = (const float*)d_in[5];
    float* out = (float*)d_out;

    char* ws = (char*)d_ws;
    u16* ws_h    = (u16*)(ws);                    // 2048*4096*2   = 16,777,216
    u16* ws_wqkv = (u16*)(ws + 16777216);         // 6144*4096*2  = 50,331,648
    u16* ws_wd   = (u16*)(ws + 67108864);         // 4096*4096*2  = 33,554,432
    u16* ws_qkv  = (u16*)(ws + 100663296);        // 2048*6144*2  = 25,165,824 (bf16)
    u16* ws_q    = (u16*)(ws + 125829120);        // 32*2048*128*2= 16,777,216
    u16* ws_k    = (u16*)(ws + 142606336);        // 8*2048*128*2 =  4,194,304
    u16* ws_v    = (u16*)(ws + 146800640);        //               =  4,194,304
    u16* ws_attn = (u16*)(ws + 150994944);        // 2048*4096*2  = 16,777,216

    cvt_bf16_kernel<<<1024, 256, 0, stream>>>(hidden,  ws_h,    (S_LEN * HID) / 4);
    cvt_bf16_kernel<<<2048, 256, 0, stream>>>(w_qkv,   ws_wqkv, (NQKV * HID) / 4);
    cvt_bf16_kernel<<<2048, 256, 0, stream>>>(w_dense, ws_wd,   (HID * HID) / 4);

    // QKV GEMM: 256^2 8-phase (grid 24x8 = 192 blocks)
    gemm_bt8_kernel<true><<<dim3(NQKV / TBN, S_LEN / TBM), 512, 0, stream>>>(
        ws_h, ws_wqkv, b_qkv, ws_qkv, S_LEN, NQKV, HID);

    rope_split_kernel<<<dim3(S_LEN, NHEADS + 2 * NKVH), 128, 0, stream>>>(
        ws_qkv, positions, ws_q, ws_k, ws_v);

    attn_bs_kernel<<<dim3(S_LEN / 64, NHEADS), 256, 0, stream>>>(ws_q, ws_k, ws_v, ws_attn);

    // dense GEMM: keep 128^2 kernel (256^2 grid would be only 128 blocks = 50% CU)
    gemm_bt_kernel<false><<<dim3(HID / BN, S_LEN / BM), 256, 0, stream>>>(
        ws_attn, ws_wd, b_dense, out, S_LEN, HID, HID);
}

// Round 5
// 553.630 us; speedup vs baseline: 1.0403x; 1.0160x over previous
//
#include <hip/hip_runtime.h>

#define S_LEN   2048
#define HID     4096
#define NHEADS  32
#define NKVH    8
#define HDIM    128
#define NQKV    6144          // NKV*(QPK+2)*HD = 8*6*128
#define ATT_SCALE (1.0f/128.0f)

typedef unsigned short u16;
typedef __attribute__((ext_vector_type(8))) __bf16 bf16x8;
typedef __attribute__((ext_vector_type(4))) float  f32x4;

__device__ __forceinline__ u16 f2bf(float f) {
    union { float f; unsigned u; } x; x.f = f;
    unsigned u = x.u;
    u += 0x7fffu + ((u >> 16) & 1u);   // round-to-nearest-even
    return (u16)(u >> 16);
}
__device__ __forceinline__ float bf2f(u16 v) {
    union { unsigned u; float f; } x; x.u = ((unsigned)v) << 16; return x.f;
}

// ---------------- fp32 -> bf16 conversion ----------------
__global__ __launch_bounds__(256) void cvt_bf16_kernel(const float* __restrict__ in,
                                                       u16* __restrict__ out, int n4) {
    int stride = gridDim.x * blockDim.x;
    for (int i = blockIdx.x * blockDim.x + threadIdx.x; i < n4; i += stride) {
        float4 v = *(const float4*)(in + (size_t)i * 4);
        ushort4 o = make_ushort4(f2bf(v.x), f2bf(v.y), f2bf(v.z), f2bf(v.w));
        *(ushort4*)(out + (size_t)i * 4) = o;
    }
}

// ---------------- 128x128 2-phase GEMM (proven ~800-900 TF) ----------------
#define BM 128
#define BN 128
#define BK 32

template <bool OUT_BF16>
__global__ __launch_bounds__(256) void gemm_bt_kernel(
    const u16* __restrict__ A,   // M x K  bf16
    const u16* __restrict__ B,   // N x K  bf16
    const float* __restrict__ bias, // N
    void* __restrict__ Cout,     // M x N  (fp32 or bf16)
    int M, int N, int K)
{
    __shared__ u16 Alds[2][BM][BK];
    __shared__ u16 Blds[2][BN][BK];

    const int tid  = threadIdx.x;
    const int wid  = tid >> 6;
    const int lane = tid & 63;
    const int ln   = lane & 15;
    const int quad = lane >> 4;
    const int wm   = (wid >> 1) * 64;
    const int wn   = (wid & 1) * 64;
    const int tileM = blockIdx.y * BM;
    const int tileN = blockIdx.x * BN;

    const int srow = lane >> 2;
    const int scol = ((lane & 3) ^ ((srow >> 1) & 3)) * 8;

    f32x4 acc[4][4];
    #pragma unroll
    for (int i = 0; i < 4; i++)
        #pragma unroll
        for (int j = 0; j < 4; j++) {
            f32x4 z = {0.f, 0.f, 0.f, 0.f};
            acc[i][j] = z;
        }

    auto stage = [&](int k, int buf) {
        const int k0 = k * BK;
        #pragma unroll
        for (int p = 0; p < 2; p++) {
            int r = p * 64 + wid * 16;
            const u16* ga = A + (size_t)(tileM + r + srow) * K + k0 + scol;
            const u16* gb = B + (size_t)(tileN + r + srow) * K + k0 + scol;
            __builtin_amdgcn_global_load_lds(
                (const __attribute__((address_space(1))) void*)ga,
                (__attribute__((address_space(3))) void*)&Alds[buf][r][0], 16, 0, 0);
            __builtin_amdgcn_global_load_lds(
                (const __attribute__((address_space(1))) void*)gb,
                (__attribute__((address_space(3))) void*)&Blds[buf][r][0], 16, 0, 0);
        }
    };

    const int nIter = K / BK;
    stage(0, 0);

    const int pc = (quad ^ ((ln >> 1) & 3)) * 8;

    for (int k = 0; k < nIter; k++) {
        const int buf = k & 1;
        __syncthreads();
        if (k + 1 < nIter) stage(k + 1, buf ^ 1);

        bf16x8 af[4], bfr[4];
        #pragma unroll
        for (int i = 0; i < 4; i++)
            af[i] = *(const bf16x8*)(&Alds[buf][wm + i * 16 + ln][pc]);
        #pragma unroll
        for (int j = 0; j < 4; j++)
            bfr[j] = *(const bf16x8*)(&Blds[buf][wn + j * 16 + ln][pc]);
        #pragma unroll
        for (int i = 0; i < 4; i++)
            #pragma unroll
            for (int j = 0; j < 4; j++)
                acc[i][j] = __builtin_amdgcn_mfma_f32_16x16x32_bf16(af[i], bfr[j], acc[i][j], 0, 0, 0);
    }

    #pragma unroll
    for (int i = 0; i < 4; i++) {
        #pragma unroll
        for (int j = 0; j < 4; j++) {
            int n = tileN + wn + j * 16 + ln;
            float bv = bias[n];
            #pragma unroll
            for (int r = 0; r < 4; r++) {
                int m = tileM + wm + i * 16 + quad * 4 + r;
                float v = acc[i][j][r] + bv;
                if (OUT_BF16)
                    ((u16*)Cout)[(size_t)m * N + n] = f2bf(v);
                else
                    ((float*)Cout)[(size_t)m * N + n] = v;
            }
        }
    }
}

// ---------------- 256x256 GEMM, 3-barrier/K-tile counted-vmcnt schedule ----------------
// 512 thr = 8 waves (2M x 4N). BK=64. LDS 128 KiB double-buffered:
//   A[buf][half][128][64] @ 0, B[buf][half][128][64] @ elem 32768.
// Round-5 restructure: with dbuf LDS, reads(tile t)->buf, stages(tile t)->bn
// never collide intra-tile; minimal sync = 3 barriers/K-tile:
//   B1 @ph0 post-vmcnt(6): h0 stages resident across ALL waves (vmcnt is
//      per-wave; other waves stage the rows this wave reads)
//   B2 @ph1 post-vmcnt(4): h1 resident
//   B3 @end-of-tile: all reads of buf complete before t+1's stages into buf
// Phases 2-3 are a barrier-free 32-MFMA register-only stretch (frags persist:
// af0/af1/bfr0/bfr1). Counted waits unchanged (ledger: 10->vmcnt(6) forces
// h0A,h0B of t; 8->vmcnt(4) forces h1A,h1B). Never vmcnt(0) in-loop; drain
// vmcnt(0) after loop (in-flight LDS-DMA at s_endpgm corrupts next WG's LDS).
// T2 swizzle (round 4, verified 0 conflicts): phys 16B chunk = logical^(row&7),
// both-sides involution, linear gload_lds dest + pre-swizzled source.
#define TBM 256
#define TBN 256
#define TBK 64

#define GFENCE() asm volatile("" ::: "memory")
#define GSBAR()  do { GFENCE(); __builtin_amdgcn_s_barrier(); GFENCE(); } while (0)

template <bool OUT_BF16>
__global__ __launch_bounds__(512, 2) void gemm_bt8_kernel(
    const u16* __restrict__ A,   // M x K  bf16
    const u16* __restrict__ B,   // N x K  bf16
    const float* __restrict__ bias,
    void* __restrict__ Cout,     // M x N
    int M, int N, int K)
{
    __shared__ u16 lds[65536];   // 128 KiB

    const int tid  = threadIdx.x;
    const int wid  = tid >> 6;        // 0..7
    const int lane = tid & 63;
    const int ln   = lane & 15;
    const int quad = lane >> 4;
    const int wr   = wid >> 2;        // 0..1 (M split)
    const int wc   = wid & 3;         // 0..3 (N split)
    const int tileM = blockIdx.y * TBM;
    const int tileN = blockIdx.x * TBN;

    f32x4 acc[2][2][4][2];            // [a][b][m][n]
    #pragma unroll
    for (int a = 0; a < 2; a++)
        #pragma unroll
        for (int b = 0; b < 2; b++)
            #pragma unroll
            for (int m = 0; m < 4; m++)
                #pragma unroll
                for (int n = 0; n < 2; n++) {
                    f32x4 z = {0.f, 0.f, 0.f, 0.f};
                    acc[a][b][m][n] = z;
                }

    const int srho = lane >> 3;                       // row within 8-row chunk (0..7)
    // source chunk pre-swizzle: row base rho0 is ≡0 (mod 8), so row&7 == srho.
    const int scol = (((lane & 7) ^ srho) << 3);      // elem col of 16B chunk

    auto stage_half = [&](const u16* Mp, int tbase, int h, int kk, int bb, int isB) {
        const int ldsbase = isB * 32768 + (bb * 2 + h) * 8192;
        #pragma unroll
        for (int s = 0; s < 2; s++) {
            const int rho0 = s * 64 + wid * 8;            // wave-uniform, ≡0 mod 8
            const int rho  = rho0 + srho;
            const u16* src = Mp + (size_t)(tbase + h * 128 + rho) * K + (size_t)kk * TBK + scol;
            __builtin_amdgcn_global_load_lds(
                (const __attribute__((address_space(1))) void*)src,
                (__attribute__((address_space(3))) void*)&lds[ldsbase + rho0 * 64], 16, 0, 0);
        }
    };

#define READ_A(a_, af_)                                                             \
    do {                                                                            \
        _Pragma("unroll")                                                           \
        for (int m = 0; m < 4; m++) {                                               \
            const int ra = wr * 64 + m * 16 + ln;                                   \
            const int ab = (buf * 2 + (a_)) * 8192 + ra * 64;                       \
            const int rx = ra & 7;                                                  \
            af_[m][0] = *(const bf16x8*)(&lds[ab + ((quad ^ rx) << 3)]);            \
            af_[m][1] = *(const bf16x8*)(&lds[ab + (((4 + quad) ^ rx) << 3)]);      \
        }                                                                           \
    } while (0)

#define READ_B(b_, bfr_)                                                            \
    do {                                                                            \
        _Pragma("unroll")                                                           \
        for (int n = 0; n < 2; n++) {                                               \
            const int rb = wc * 32 + n * 16 + ln;                                   \
            const int bbase = 32768 + (buf * 2 + (b_)) * 8192 + rb * 64;            \
            const int rx = rb & 7;                                                  \
            bfr_[n][0] = *(const bf16x8*)(&lds[bbase + ((quad ^ rx) << 3)]);        \
            bfr_[n][1] = *(const bf16x8*)(&lds[bbase + (((4 + quad) ^ rx) << 3)]);  \
        }                                                                           \
    } while (0)

#define DO_MFMA(a_, b_, af_, bfr_)                                                  \
    do {                                                                            \
        __builtin_amdgcn_s_setprio(1);                                              \
        _Pragma("unroll")                                                           \
        for (int m = 0; m < 4; m++)                                                 \
            _Pragma("unroll")                                                       \
            for (int n = 0; n < 2; n++) {                                           \
                acc[a_][b_][m][n] = __builtin_amdgcn_mfma_f32_16x16x32_bf16(        \
                    af_[m][0], bfr_[n][0], acc[a_][b_][m][n], 0, 0, 0);             \
                acc[a_][b_][m][n] = __builtin_amdgcn_mfma_f32_16x16x32_bf16(        \
                    af_[m][1], bfr_[n][1], acc[a_][b_][m][n], 0, 0, 0);             \
            }                                                                       \
        __builtin_amdgcn_s_setprio(0);                                              \
    } while (0)

    const int nIter = K / TBK;

    // prologue: stage K-tile 0 into buf0 (order matters for vmcnt counting)
    stage_half(A, tileM, 0, 0, 0, 0);
    stage_half(B, tileN, 0, 0, 0, 1);
    stage_half(A, tileM, 1, 0, 0, 0);
    stage_half(B, tileN, 1, 0, 0, 1);

    bf16x8 af0[4][2], af1[4][2], bfr0[2][2], bfr1[2][2];

    for (int t = 0; t < nIter; t++) {
        const int buf = t & 1;
        const int bn  = buf ^ 1;
        const int kn  = (t + 1 == nIter) ? 0 : t + 1;   // final-iter dummy keeps counts uniform

        // ---- phase 0: Q(0,0) — needs A-h0,B-h0 of tile t ----
        stage_half(A, tileM, 0, kn, bn, 0);
        asm volatile("s_waitcnt vmcnt(6)" ::: "memory");   // force A-h0,B-h0 (this wave)
        GSBAR();                                            // ... across all waves
        READ_A(0, af0); READ_B(0, bfr0);
        DO_MFMA(0, 0, af0, bfr0);

        // ---- phase 1: Q(1,0) — needs A-h1 (B-h0 frags reused) ----
        stage_half(B, tileN, 0, kn, bn, 1);
        asm volatile("s_waitcnt vmcnt(4)" ::: "memory");   // force A-h1,B-h1
        GSBAR();
        READ_A(1, af1); READ_B(1, bfr1);                    // af1 first: Q(1,0) needs it
        DO_MFMA(1, 0, af1, bfr0);

        // ---- phase 2: Q(1,1) — register-only, no barrier ----
        stage_half(A, tileM, 1, kn, bn, 0);
        DO_MFMA(1, 1, af1, bfr1);

        // ---- phase 3: Q(0,1) — register-only ----
        stage_half(B, tileN, 1, kn, bn, 1);
        DO_MFMA(0, 1, af0, bfr1);

        asm volatile("s_waitcnt lgkmcnt(0)" ::: "memory");  // all buf reads complete
        GSBAR();                                            // before t+1 stages into buf
    }

    // CRITICAL drain: the last iteration's dummy stages are still in flight;
    // LDS-DMA landing after s_endpgm would corrupt the next workgroup's LDS.
    asm volatile("s_waitcnt vmcnt(0)" ::: "memory");

#undef READ_A
#undef READ_B
#undef DO_MFMA

    // epilogue
    #pragma unroll
    for (int a = 0; a < 2; a++)
        #pragma unroll
        for (int b = 0; b < 2; b++)
            #pragma unroll
            for (int n = 0; n < 2; n++) {
                #pragma unroll
                for (int m = 0; m < 4; m++) {
                    const int col = tileN + b * 128 + wc * 32 + n * 16 + ln;
                    const float bv = bias[col];
                    #pragma unroll
                    for (int r = 0; r < 4; r++) {
                        const int row = tileM + a * 128 + wr * 64 + m * 16 + quad * 4 + r;
                        float v = acc[a][b][m][n][r] + bv;
                        if (OUT_BF16)
                            ((u16*)Cout)[(size_t)row * N + col] = f2bf(v);
                        else
                            ((float*)Cout)[(size_t)row * N + col] = v;
                    }
                }
            }
}

// ---------------- RoPE + split qkv (bf16 in, bf16 out) ----------------
__global__ __launch_bounds__(128) void rope_split_kernel(
    const u16* __restrict__ qkv, const int* __restrict__ positions,
    u16* __restrict__ qb_o, u16* __restrict__ kb_o, u16* __restrict__ vb_o)
{
    const int d   = threadIdx.x;     // 0..127
    const int pos = blockIdx.x;      // 0..S-1
    const int hy  = blockIdx.y;      // 0..47
    const float p = (float)positions[pos];

    if (hy >= NHEADS + NKVH) {               // v copy
        int kv = hy - NHEADS - NKVH;
        const u16* src = qkv + (size_t)pos * NQKV + (kv * 6 + 5) * HDIM;
        vb_o[((size_t)kv * S_LEN + pos) * HDIM + d] = src[d];
        return;
    }
    const u16* src;
    u16* dst;
    if (hy < NHEADS) {                        // q head
        int kv = hy >> 2, qi = hy & 3;
        src = qkv + (size_t)pos * NQKV + (kv * 6 + qi) * HDIM;
        dst = qb_o + ((size_t)hy * S_LEN + pos) * HDIM;
    } else {                                  // k head
        int kv = hy - NHEADS;
        src = qkv + (size_t)pos * NQKV + (kv * 6 + 4) * HDIM;
        dst = kb_o + ((size_t)kv * S_LEN + pos) * HDIM;
    }
    int d2 = d & 63;
    float inv = expf(-(float)d2 * (13.815510557964274f / 64.0f)); // 1e6^(-d2/64)
    float fr = p * inv;
    float s, c;
    sincosf(fr, &s, &c);
    float x1 = bf2f(src[d2]);
    float x2 = bf2f(src[d2 + 64]);
    float o = (d < 64) ? (x1 * c - x2 * s) : (x2 * c + x1 * s);
    dst[d] = f2bf(o);
}

// ---------------- blocksparse flash attention ----------------
// grid (S/64, NH); block 256 (4 waves). Wave w owns query rows w*16..w*16+15.
// Q in regs; K via gload_lds + XOR swizzle; Vt/P swizzled; 2 barriers/tile;
// LDS 40960 B -> 4 blocks/CU; qb reversed; setprio on MFMA clusters.
__global__ __launch_bounds__(256, 4) void attn_bs_kernel(
    const u16* __restrict__ Q,   // (NH, S, HD) bf16
    const u16* __restrict__ K,   // (NKV, S, HD)
    const u16* __restrict__ V,   // (NKV, S, HD)
    u16* __restrict__ O)         // (S, NH*HD) bf16
{
    __shared__ u16 Ks[64 * 128];      // 16 KB, swizzled
    __shared__ u16 Vt[128 * 64];      // 16 KB, V^T, swizzled
    __shared__ u16 Ps[4][16 * 64];    // 8 KB, per-wave P, swizzled

    const int qb = (int)gridDim.x - 1 - (int)blockIdx.x;   // heavy blocks first
    const int h  = blockIdx.y;
    const int kv = h >> 2;
    const int tid  = threadIdx.x;
    const int w    = tid >> 6;
    const int lane = tid & 63;
    const int ln   = lane & 15;
    const int quad = lane >> 4;

    bf16x8 aq[4];
    {
        const u16* Qg = Q + ((size_t)h * S_LEN + qb * 64 + w * 16 + ln) * HDIM + quad * 8;
        #pragma unroll
        for (int ks = 0; ks < 4; ks++)
            aq[ks] = *(const bf16x8*)(Qg + ks * 32);
    }

    f32x4 oacc[8];
    #pragma unroll
    for (int n = 0; n < 8; n++) { f32x4 z = {0.f,0.f,0.f,0.f}; oacc[n] = z; }
    float mrow[4] = {-1e30f, -1e30f, -1e30f, -1e30f};
    float lrow[4] = {0.f, 0.f, 0.f, 0.f};

    for (int kb = 0; kb <= qb; kb++) {
        bool sel = (qb - kb < 16) || (((kb + h + 1) & 7) == 0);
        if (!sel) continue;

        __syncthreads();   // previous iteration's LDS reads complete

        const u16* Kg = K + ((size_t)kv * S_LEN + kb * 64) * HDIM;
        const u16* Vg = V + ((size_t)kv * S_LEN + kb * 64) * HDIM;

        #pragma unroll
        for (int p = 0; p < 4; p++) {
            int r0  = w * 16 + p * 4;
            int row = r0 + (lane >> 4);
            const u16* src = Kg + (size_t)row * HDIM + (((lane & 15) ^ (row & 7)) << 3);
            __builtin_amdgcn_global_load_lds(
                (const __attribute__((address_space(1))) void*)src,
                (__attribute__((address_space(3))) void*)&Ks[r0 * 128], 16, 0, 0);
        }

        {
            int dbase = w * 32;
            #pragma unroll
            for (int p = 0; p < 4; p++) {
                int d0 = dbase + p * 8;
                uint4 vv = *(const uint4*)(Vg + (size_t)lane * HDIM + d0);
                const u16* pvv = (const u16*)&vv;
                #pragma unroll
                for (int jj = 0; jj < 8; jj++) {
                    int d = d0 + jj;
                    Vt[d * 64 + ((((lane >> 3)) ^ (d & 7)) << 3) + (lane & 7)] = pvv[jj];
                }
            }
        }
        __syncthreads();

        f32x4 sacc[4];
        #pragma unroll
        for (int jj = 0; jj < 4; jj++) { f32x4 z = {0.f,0.f,0.f,0.f}; sacc[jj] = z; }
        __builtin_amdgcn_s_setprio(1);
        #pragma unroll
        for (int ks = 0; ks < 4; ks++) {
            #pragma unroll
            for (int jj = 0; jj < 4; jj++) {
                bf16x8 bk = *(const bf16x8*)(
                    &Ks[(jj * 16 + ln) * 128 + (((ks * 4 + quad) ^ (ln & 7)) << 3)]);
                sacc[jj] = __builtin_amdgcn_mfma_f32_16x16x32_bf16(aq[ks], bk, sacc[jj], 0, 0, 0);
            }
        }
        __builtin_amdgcn_s_setprio(0);

        #pragma unroll
        for (int r = 0; r < 4; r++) {
            float pv[4];
            float mx = -1e30f;
            const int qrow = w * 16 + quad * 4 + r;
            #pragma unroll
            for (int jj = 0; jj < 4; jj++) {
                float s = sacc[jj][r] * ATT_SCALE;
                if (kb == qb && (jj * 16 + ln) > qrow) s = -1e30f;
                pv[jj] = s;
                mx = fmaxf(mx, s);
            }
            #pragma unroll
            for (int off = 1; off < 16; off <<= 1)
                mx = fmaxf(mx, __shfl_xor(mx, off, 64));
            float mnew  = fmaxf(mrow[r], mx);
            float alpha = __expf(mrow[r] - mnew);
            float sum = 0.f;
            #pragma unroll
            for (int jj = 0; jj < 4; jj++) {
                float pe = __expf(pv[jj] - mnew);
                pv[jj] = pe;
                sum += pe;
            }
            #pragma unroll
            for (int off = 1; off < 16; off <<= 1)
                sum += __shfl_xor(sum, off, 64);
            lrow[r] = lrow[r] * alpha + sum;
            mrow[r] = mnew;
            #pragma unroll
            for (int n = 0; n < 8; n++) oacc[n][r] *= alpha;
            const int prow = quad * 4 + r;
            #pragma unroll
            for (int jj = 0; jj < 4; jj++)
                Ps[w][prow * 64 + (((jj * 2 + (ln >> 3)) ^ (prow & 7)) << 3) + (ln & 7)]
                    = f2bf(pv[jj]);
        }
        // no barrier: Ps[w] is written and read only by wave w (in-order DS pipe)

        __builtin_amdgcn_s_setprio(1);
        #pragma unroll
        for (int kk = 0; kk < 2; kk++) {
            bf16x8 ap = *(const bf16x8*)(
                &Ps[w][ln * 64 + (((kk * 4 + quad) ^ (ln & 7)) << 3)]);
            #pragma unroll
            for (int n = 0; n < 8; n++) {
                bf16x8 bv = *(const bf16x8*)(
                    &Vt[(n * 16 + ln) * 64 + (((kk * 4 + quad) ^ (ln & 7)) << 3)]);
                oacc[n] = __builtin_amdgcn_mfma_f32_16x16x32_bf16(ap, bv, oacc[n], 0, 0, 0);
            }
        }
        __builtin_amdgcn_s_setprio(0);
    }

    #pragma unroll
    for (int n = 0; n < 8; n++) {
        #pragma unroll
        for (int r = 0; r < 4; r++) {
            int row = w * 16 + quad * 4 + r;
            int pos = qb * 64 + row;
            float o = oacc[n][r] / lrow[r];
            O[(size_t)pos * (NHEADS * HDIM) + h * HDIM + n * 16 + ln] = f2bf(o);
        }
    }
}

// ---------------- launch ----------------
extern "C" void kernel_launch(void* const* d_in, const int* in_sizes, int n_in,
                              void* d_out, int out_size, void* d_ws, size_t ws_size,
                              hipStream_t stream) {
    const int*   positions = (const int*)d_in[0];
    const float* hidden    = (const float*)d_in[1];
    const float* w_qkv     = (const float*)d_in[2];
    const float* b_qkv     = (const float*)d_in[3];
    const float* w_dense   = (const float*)d_in[4];
    const float* b_dense   = (const float*)d_in[5];
    float* out = (float*)d_out;

    char* ws = (char*)d_ws;
    u16* ws_h    = (u16*)(ws);                    // 2048*4096*2   = 16,777,216
    u16* ws_wqkv = (u16*)(ws + 16777216);         // 6144*4096*2  = 50,331,648
    u16* ws_wd   = (u16*)(ws + 67108864);         // 4096*4096*2  = 33,554,432
    u16* ws_qkv  = (u16*)(ws + 100663296);        // 2048*6144*2  = 25,165,824 (bf16)
    u16* ws_q    = (u16*)(ws + 125829120);        // 32*2048*128*2= 16,777,216
    u16* ws_k    = (u16*)(ws + 142606336);        // 8*2048*128*2 =  4,194,304
    u16* ws_v    = (u16*)(ws + 146800640);        //               =  4,194,304
    u16* ws_attn = (u16*)(ws + 150994944);        // 2048*4096*2  = 16,777,216

    cvt_bf16_kernel<<<1024, 256, 0, stream>>>(hidden,  ws_h,    (S_LEN * HID) / 4);
    cvt_bf16_kernel<<<2048, 256, 0, stream>>>(w_qkv,   ws_wqkv, (NQKV * HID) / 4);
    cvt_bf16_kernel<<<2048, 256, 0, stream>>>(w_dense, ws_wd,   (HID * HID) / 4);

    // QKV GEMM: 256^2 3-barrier counted-vmcnt (grid 24x8 = 192 blocks)
    gemm_bt8_kernel<true><<<dim3(NQKV / TBN, S_LEN / TBM), 512, 0, stream>>>(
        ws_h, ws_wqkv, b_qkv, ws_qkv, S_LEN, NQKV, HID);

    rope_split_kernel<<<dim3(S_LEN, NHEADS + 2 * NKVH), 128, 0, stream>>>(
        ws_qkv, positions, ws_q, ws_k, ws_v);

    attn_bs_kernel<<<dim3(S_LEN / 64, NHEADS), 256, 0, stream>>>(ws_q, ws_k, ws_v, ws_attn);

    // dense GEMM: keep 128^2 kernel (256^2 grid would be only 128 blocks = 50% CU)
    gemm_bt_kernel<false><<<dim3(HID / BN, S_LEN / BM), 256, 0, stream>>>(
        ws_attn, ws_wd, b_dense, out, S_LEN, HID, HID);
}

// Round 7
// 520.894 us; speedup vs baseline: 1.1057x; 1.0628x over previous
//
#include <hip/hip_runtime.h>

#define S_LEN   2048
#define HID     4096
#define NHEADS  32
#define NKVH    8
#define HDIM    128
#define NQKV    6144          // NKV*(QPK+2)*HD = 8*6*128
#define ATT_SCALE (1.0f/128.0f)

typedef unsigned short u16;
typedef __attribute__((ext_vector_type(8))) __bf16 bf16x8;
typedef __attribute__((ext_vector_type(4))) float  f32x4;

__device__ __forceinline__ u16 f2bf(float f) {
    union { float f; unsigned u; } x; x.f = f;
    unsigned u = x.u;
    u += 0x7fffu + ((u >> 16) & 1u);   // round-to-nearest-even
    return (u16)(u >> 16);
}
__device__ __forceinline__ float bf2f(u16 v) {
    union { unsigned u; float f; } x; x.u = ((unsigned)v) << 16; return x.f;
}

// ---------------- fp32 -> bf16 conversion ----------------
__global__ __launch_bounds__(256) void cvt_bf16_kernel(const float* __restrict__ in,
                                                       u16* __restrict__ out, int n4) {
    int stride = gridDim.x * blockDim.x;
    for (int i = blockIdx.x * blockDim.x + threadIdx.x; i < n4; i += stride) {
        float4 v = *(const float4*)(in + (size_t)i * 4);
        ushort4 o = make_ushort4(f2bf(v.x), f2bf(v.y), f2bf(v.z), f2bf(v.w));
        *(ushort4*)(out + (size_t)i * 4) = o;
    }
}

// ---------------- full-coverage GEMM: 128 x BN tile, counted-vmcnt schedule ----------------
// Round-7 = round-6 logic (audited: ledger, OOB, barriers all correct) with
// peak-VGPR reduction: B-fragments STREAMED per-n (one bfr pair live, not
// NB_) to eliminate any chance of in-loop scratch spill. Spilled scratch ops
// enter the vmcnt FIFO and silently break the counted waits — the one fault
// class the round-6 audit could not exclude.
//   BM=128, BN=N/16 (QKV 384, dense 256), BK=64, 512 thr = 8 waves (2M x 4N).
//   Per-wave output 64 x 2*NB*16. A staged once per tile (af read once,
//   reused across both b-phases).
// LDS: A[2buf][128][64] @ 0; B[2buf][BN][64] @ elem 16384. QKV 128 KiB.
// Sync per K-tile (3 barriers):
//   P0: stage A(t+1); vmcnt(2+LB) [10/8 outstanding -> forces A(t),B0(t)];
//       barrier; read af; MFMA b=0 (stream bfr).
//   P1: stage B0(t+1); vmcnt(2+LB) [forces B1(t)]; barrier; MFMA b=1;
//       stage B1(t+1).
//   end: lgkmcnt(0); barrier.
// Never vmcnt(0) in-loop (T4); drain vmcnt(0) after loop (in-flight LDS-DMA
// at s_endpgm faults/corrupts the next WG — round-2 root cause).
// T2 swizzle (verified 0 conflicts): phys 16B chunk = logical^(row&7),
// both-sides involution: linear gload_lds dest + pre-swizzled source + XOR read.
#define GFENCE() asm volatile("" ::: "memory")
#define GSBAR()  do { GFENCE(); __builtin_amdgcn_s_barrier(); GFENCE(); } while (0)

template <int BN_, int NB_, bool OUT_BF16>
__global__ __launch_bounds__(512, 2) void gemm_fc_kernel(
    const u16* __restrict__ A,   // M x K  bf16
    const u16* __restrict__ B,   // N x K  bf16
    const float* __restrict__ bias,
    void* __restrict__ Cout,     // M x N
    int M, int N, int K)
{
    constexpr int LB = BN_ / 128;          // gload_lds per B-half per wave
    constexpr int VM = 2 + LB;             // counted-wait value (5 or 4)
    __shared__ u16 lds[16384 + 2 * BN_ * 64];

    const int tid  = threadIdx.x;
    const int wid  = tid >> 6;        // 0..7
    const int lane = tid & 63;
    const int ln   = lane & 15;
    const int quad = lane >> 4;
    const int wr   = wid >> 2;        // 0..1 (M split)
    const int wc   = wid & 3;         // 0..3 (N split)
    const int tileM = blockIdx.y * 128;
    const int tileN = blockIdx.x * BN_;

    f32x4 acc[2][NB_][4];             // [b][n][m]
    #pragma unroll
    for (int b = 0; b < 2; b++)
        #pragma unroll
        for (int n = 0; n < NB_; n++)
            #pragma unroll
            for (int m = 0; m < 4; m++) {
                f32x4 z = {0.f, 0.f, 0.f, 0.f};
                acc[b][n][m] = z;
            }

    const int srho = lane >> 3;                       // row within 8-row group
    const int scol = (((lane & 7) ^ srho) << 3);      // pre-swizzled source chunk

    auto gload = [&](const u16* src, u16* dst) {
        __builtin_amdgcn_global_load_lds(
            (const __attribute__((address_space(1))) void*)src,
            (__attribute__((address_space(3))) void*)dst, 16, 0, 0);
    };
    // A unit: 128 rows, 2 loads/wave
    auto stage_A = [&](int kk, int bb) {
        const int base = bb * 8192;
        #pragma unroll
        for (int s = 0; s < 2; s++) {
            const int rho0 = s * 64 + wid * 8;        // wave-uniform, ≡0 mod 8
            const int rho  = rho0 + srho;
            const u16* src = A + (size_t)(tileM + rho) * K + (size_t)kk * 64 + scol;
            gload(src, &lds[base + rho0 * 64]);
        }
    };
    // B half h: BN/2 rows, LB loads/wave
    auto stage_Bh = [&](int h, int kk, int bb) {
        const int base = 16384 + bb * (BN_ * 64) + h * ((BN_ / 2) * 64);
        #pragma unroll
        for (int s = 0; s < LB; s++) {
            const int rho0 = s * 64 + wid * 8;
            const int rho  = rho0 + srho;
            const u16* src = B + (size_t)(tileN + h * (BN_ / 2) + rho) * K
                               + (size_t)kk * 64 + scol;
            gload(src, &lds[base + rho0 * 64]);
        }
    };

#define WAIT_VM()                                                                   \
    do {                                                                            \
        if constexpr (VM == 5) asm volatile("s_waitcnt vmcnt(5)" ::: "memory");     \
        else                   asm volatile("s_waitcnt vmcnt(4)" ::: "memory");     \
    } while (0)

#define READ_A()                                                                    \
    do {                                                                            \
        _Pragma("unroll")                                                           \
        for (int m = 0; m < 4; m++) {                                               \
            const int ra = wr * 64 + m * 16 + ln;                                   \
            const int ab = buf * 8192 + ra * 64;                                    \
            const int rx = ra & 7;                                                  \
            af[m][0] = *(const bf16x8*)(&lds[ab + ((quad ^ rx) << 3)]);             \
            af[m][1] = *(const bf16x8*)(&lds[ab + (((4 + quad) ^ rx) << 3)]);       \
        }                                                                           \
    } while (0)

// streamed: one bfr pair live at a time (peak frag VGPRs 40, was 56)
#define MFMA_B(b_)                                                                  \
    do {                                                                            \
        __builtin_amdgcn_s_setprio(1);                                              \
        _Pragma("unroll")                                                           \
        for (int n = 0; n < NB_; n++) {                                             \
            const int rb = (b_) * (BN_ / 2) + wc * (NB_ * 16) + n * 16 + ln;        \
            const int bb = 16384 + buf * (BN_ * 64) + rb * 64;                      \
            const int rx = rb & 7;                                                  \
            bf16x8 b0 = *(const bf16x8*)(&lds[bb + ((quad ^ rx) << 3)]);            \
            bf16x8 b1 = *(const bf16x8*)(&lds[bb + (((4 + quad) ^ rx) << 3)]);      \
            _Pragma("unroll")                                                       \
            for (int m = 0; m < 4; m++) {                                           \
                acc[b_][n][m] = __builtin_amdgcn_mfma_f32_16x16x32_bf16(            \
                    af[m][0], b0, acc[b_][n][m], 0, 0, 0);                          \
                acc[b_][n][m] = __builtin_amdgcn_mfma_f32_16x16x32_bf16(            \
                    af[m][1], b1, acc[b_][n][m], 0, 0, 0);                          \
            }                                                                       \
        }                                                                           \
        __builtin_amdgcn_s_setprio(0);                                              \
    } while (0)

    const int nIter = K / 64;

    // prologue: tile 0 -> buf0, order A, B0, B1 (order matters for the ledger)
    stage_A(0, 0); stage_Bh(0, 0, 0); stage_Bh(1, 0, 0);

    bf16x8 af[4][2];

    for (int t = 0; t < nIter; t++) {
        const int buf = t & 1;
        const int bn  = buf ^ 1;
        const int kn  = (t + 1 == nIter) ? 0 : t + 1;   // final-iter dummy keeps counts uniform

        // ---- P0: b=0 needs A(t) + B0(t) ----
        stage_A(kn, bn);
        WAIT_VM();             // outstanding 2*2+2*LB -> forces A(t), B0(t)
        GSBAR();
        READ_A();
        MFMA_B(0);

        // ---- P1: b=1 needs B1(t); af reused ----
        stage_Bh(0, kn, bn);
        WAIT_VM();             // outstanding LB+2+LB -> forces B1(t)
        GSBAR();
        MFMA_B(1);
        stage_Bh(1, kn, bn);

        asm volatile("s_waitcnt lgkmcnt(0)" ::: "memory");  // all buf reads complete
        GSBAR();                                            // before t+1 DMAs into buf
    }

    // CRITICAL drain: final-iter dummy stages still in flight; LDS-DMA landing
    // after s_endpgm faults / corrupts the next workgroup's LDS.
    asm volatile("s_waitcnt vmcnt(0)" ::: "memory");

#undef WAIT_VM
#undef READ_A
#undef MFMA_B

    // epilogue
    #pragma unroll
    for (int b = 0; b < 2; b++)
        #pragma unroll
        for (int n = 0; n < NB_; n++) {
            const int col = tileN + b * (BN_ / 2) + wc * (NB_ * 16) + n * 16 + ln;
            const float bv = bias[col];
            #pragma unroll
            for (int m = 0; m < 4; m++) {
                #pragma unroll
                for (int r = 0; r < 4; r++) {
                    const int row = tileM + wr * 64 + m * 16 + quad * 4 + r;
                    float v = acc[b][n][m][r] + bv;
                    if (OUT_BF16)
                        ((u16*)Cout)[(size_t)row * N + col] = f2bf(v);
                    else
                        ((float*)Cout)[(size_t)row * N + col] = v;
                }
            }
        }
}

// ---------------- RoPE + split qkv (bf16 in, bf16 out) ----------------
__global__ __launch_bounds__(128) void rope_split_kernel(
    const u16* __restrict__ qkv, const int* __restrict__ positions,
    u16* __restrict__ qb_o, u16* __restrict__ kb_o, u16* __restrict__ vb_o)
{
    const int d   = threadIdx.x;     // 0..127
    const int pos = blockIdx.x;      // 0..S-1
    const int hy  = blockIdx.y;      // 0..47
    const float p = (float)positions[pos];

    if (hy >= NHEADS + NKVH) {               // v copy
        int kv = hy - NHEADS - NKVH;
        const u16* src = qkv + (size_t)pos * NQKV + (kv * 6 + 5) * HDIM;
        vb_o[((size_t)kv * S_LEN + pos) * HDIM + d] = src[d];
        return;
    }
    const u16* src;
    u16* dst;
    if (hy < NHEADS) {                        // q head
        int kv = hy >> 2, qi = hy & 3;
        src = qkv + (size_t)pos * NQKV + (kv * 6 + qi) * HDIM;
        dst = qb_o + ((size_t)hy * S_LEN + pos) * HDIM;
    } else {                                  // k head
        int kv = hy - NHEADS;
        src = qkv + (size_t)pos * NQKV + (kv * 6 + 4) * HDIM;
        dst = kb_o + ((size_t)kv * S_LEN + pos) * HDIM;
    }
    int d2 = d & 63;
    float inv = expf(-(float)d2 * (13.815510557964274f / 64.0f)); // 1e6^(-d2/64)
    float fr = p * inv;
    float s, c;
    sincosf(fr, &s, &c);
    float x1 = bf2f(src[d2]);
    float x2 = bf2f(src[d2 + 64]);
    float o = (d < 64) ? (x1 * c - x2 * s) : (x2 * c + x1 * s);
    dst[d] = f2bf(o);
}

// ---------------- blocksparse flash attention ----------------
// grid (S/64, NH); block 256 (4 waves). Wave w owns query rows w*16..w*16+15.
// Q in regs; K via gload_lds + XOR swizzle; Vt/P swizzled; 2 barriers/tile;
// LDS 40960 B -> 4 blocks/CU; qb reversed; setprio on MFMA clusters.
__global__ __launch_bounds__(256, 4) void attn_bs_kernel(
    const u16* __restrict__ Q,   // (NH, S, HD) bf16
    const u16* __restrict__ K,   // (NKV, S, HD)
    const u16* __restrict__ V,   // (NKV, S, HD)
    u16* __restrict__ O)         // (S, NH*HD) bf16
{
    __shared__ u16 Ks[64 * 128];      // 16 KB, swizzled
    __shared__ u16 Vt[128 * 64];      // 16 KB, V^T, swizzled
    __shared__ u16 Ps[4][16 * 64];    // 8 KB, per-wave P, swizzled

    const int qb = (int)gridDim.x - 1 - (int)blockIdx.x;   // heavy blocks first
    const int h  = blockIdx.y;
    const int kv = h >> 2;
    const int tid  = threadIdx.x;
    const int w    = tid >> 6;
    const int lane = tid & 63;
    const int ln   = lane & 15;
    const int quad = lane >> 4;

    bf16x8 aq[4];
    {
        const u16* Qg = Q + ((size_t)h * S_LEN + qb * 64 + w * 16 + ln) * HDIM + quad * 8;
        #pragma unroll
        for (int ks = 0; ks < 4; ks++)
            aq[ks] = *(const bf16x8*)(Qg + ks * 32);
    }

    f32x4 oacc[8];
    #pragma unroll
    for (int n = 0; n < 8; n++) { f32x4 z = {0.f,0.f,0.f,0.f}; oacc[n] = z; }
    float mrow[4] = {-1e30f, -1e30f, -1e30f, -1e30f};
    float lrow[4] = {0.f, 0.f, 0.f, 0.f};

    for (int kb = 0; kb <= qb; kb++) {
        bool sel = (qb - kb < 16) || (((kb + h + 1) & 7) == 0);
        if (!sel) continue;

        __syncthreads();   // previous iteration's LDS reads complete

        const u16* Kg = K + ((size_t)kv * S_LEN + kb * 64) * HDIM;
        const u16* Vg = V + ((size_t)kv * S_LEN + kb * 64) * HDIM;

        #pragma unroll
        for (int p = 0; p < 4; p++) {
            int r0  = w * 16 + p * 4;
            int row = r0 + (lane >> 4);
            const u16* src = Kg + (size_t)row * HDIM + (((lane & 15) ^ (row & 7)) << 3);
            __builtin_amdgcn_global_load_lds(
                (const __attribute__((address_space(1))) void*)src,
                (__attribute__((address_space(3))) void*)&Ks[r0 * 128], 16, 0, 0);
        }

        {
            int dbase = w * 32;
            #pragma unroll
            for (int p = 0; p < 4; p++) {
                int d0 = dbase + p * 8;
                uint4 vv = *(const uint4*)(Vg + (size_t)lane * HDIM + d0);
                const u16* pvv = (const u16*)&vv;
                #pragma unroll
                for (int jj = 0; jj < 8; jj++) {
                    int d = d0 + jj;
                    Vt[d * 64 + ((((lane >> 3)) ^ (d & 7)) << 3) + (lane & 7)] = pvv[jj];
                }
            }
        }
        __syncthreads();

        f32x4 sacc[4];
        #pragma unroll
        for (int jj = 0; jj < 4; jj++) { f32x4 z = {0.f,0.f,0.f,0.f}; sacc[jj] = z; }
        __builtin_amdgcn_s_setprio(1);
        #pragma unroll
        for (int ks = 0; ks < 4; ks++) {
            #pragma unroll
            for (int jj = 0; jj < 4; jj++) {
                bf16x8 bk = *(const bf16x8*)(
                    &Ks[(jj * 16 + ln) * 128 + (((ks * 4 + quad) ^ (ln & 7)) << 3)]);
                sacc[jj] = __builtin_amdgcn_mfma_f32_16x16x32_bf16(aq[ks], bk, sacc[jj], 0, 0, 0);
            }
        }
        __builtin_amdgcn_s_setprio(0);

        #pragma unroll
        for (int r = 0; r < 4; r++) {
            float pv[4];
            float mx = -1e30f;
            const int qrow = w * 16 + quad * 4 + r;
            #pragma unroll
            for (int jj = 0; jj < 4; jj++) {
                float s = sacc[jj][r] * ATT_SCALE;
                if (kb == qb && (jj * 16 + ln) > qrow) s = -1e30f;
                pv[jj] = s;
                mx = fmaxf(mx, s);
            }
            #pragma unroll
            for (int off = 1; off < 16; off <<= 1)
                mx = fmaxf(mx, __shfl_xor(mx, off, 64));
            float mnew  = fmaxf(mrow[r], mx);
            float alpha = __expf(mrow[r] - mnew);
            float sum = 0.f;
            #pragma unroll
            for (int jj = 0; jj < 4; jj++) {
                float pe = __expf(pv[jj] - mnew);
                pv[jj] = pe;
                sum += pe;
            }
            #pragma unroll
            for (int off = 1; off < 16; off <<= 1)
                sum += __shfl_xor(sum, off, 64);
            lrow[r] = lrow[r] * alpha + sum;
            mrow[r] = mnew;
            #pragma unroll
            for (int n = 0; n < 8; n++) oacc[n][r] *= alpha;
            const int prow = quad * 4 + r;
            #pragma unroll
            for (int jj = 0; jj < 4; jj++)
                Ps[w][prow * 64 + (((jj * 2 + (ln >> 3)) ^ (prow & 7)) << 3) + (ln & 7)]
                    = f2bf(pv[jj]);
        }
        // no barrier: Ps[w] is written and read only by wave w (in-order DS pipe)

        __builtin_amdgcn_s_setprio(1);
        #pragma unroll
        for (int kk = 0; kk < 2; kk++) {
            bf16x8 ap = *(const bf16x8*)(
                &Ps[w][ln * 64 + (((kk * 4 + quad) ^ (ln & 7)) << 3)]);
            #pragma unroll
            for (int n = 0; n < 8; n++) {
                bf16x8 bv = *(const bf16x8*)(
                    &Vt[(n * 16 + ln) * 64 + (((kk * 4 + quad) ^ (ln & 7)) << 3)]);
                oacc[n] = __builtin_amdgcn_mfma_f32_16x16x32_bf16(ap, bv, oacc[n], 0, 0, 0);
            }
        }
        __builtin_amdgcn_s_setprio(0);
    }

    #pragma unroll
    for (int n = 0; n < 8; n++) {
        #pragma unroll
        for (int r = 0; r < 4; r++) {
            int row = w * 16 + quad * 4 + r;
            int pos = qb * 64 + row;
            float o = oacc[n][r] / lrow[r];
            O[(size_t)pos * (NHEADS * HDIM) + h * HDIM + n * 16 + ln] = f2bf(o);
        }
    }
}

// ---------------- launch ----------------
extern "C" void kernel_launch(void* const* d_in, const int* in_sizes, int n_in,
                              void* d_out, int out_size, void* d_ws, size_t ws_size,
                              hipStream_t stream) {
    const int*   positions = (const int*)d_in[0];
    const float* hidden    = (const float*)d_in[1];
    const float* w_qkv     = (const float*)d_in[2];
    const float* b_qkv     = (const float*)d_in[3];
    const float* w_dense   = (const float*)d_in[4];
    const float* b_dense   = (const float*)d_in[5];
    float* out = (float*)d_out;

    char* ws = (char*)d_ws;
    u16* ws_h    = (u16*)(ws);                    // 2048*4096*2   = 16,777,216
    u16* ws_wqkv = (u16*)(ws + 16777216);         // 6144*4096*2  = 50,331,648
    u16* ws_wd   = (u16*)(ws + 67108864);         // 4096*4096*2  = 33,554,432
    u16* ws_qkv  = (u16*)(ws + 100663296);        // 2048*6144*2  = 25,165,824 (bf16)
    u16* ws_q    = (u16*)(ws + 125829120);        // 32*2048*128*2= 16,777,216
    u16* ws_k    = (u16*)(ws + 142606336);        // 8*2048*128*2 =  4,194,304
    u16* ws_v    = (u16*)(ws + 146800640);        //               =  4,194,304
    u16* ws_attn = (u16*)(ws + 150994944);        // 2048*4096*2  = 16,777,216

    cvt_bf16_kernel<<<1024, 256, 0, stream>>>(hidden,  ws_h,    (S_LEN * HID) / 4);
    cvt_bf16_kernel<<<2048, 256, 0, stream>>>(w_qkv,   ws_wqkv, (NQKV * HID) / 4);
    cvt_bf16_kernel<<<2048, 256, 0, stream>>>(w_dense, ws_wd,   (HID * HID) / 4);

    // QKV GEMM: 128x384 tile -> grid 16x16 = 256 blocks (full CU coverage)
    gemm_fc_kernel<384, 3, true><<<dim3(NQKV / 384, S_LEN / 128), 512, 0, stream>>>(
        ws_h, ws_wqkv, b_qkv, ws_qkv, S_LEN, NQKV, HID);

    rope_split_kernel<<<dim3(S_LEN, NHEADS + 2 * NKVH), 128, 0, stream>>>(
        ws_qkv, positions, ws_q, ws_k, ws_v);

    attn_bs_kernel<<<dim3(S_LEN / 64, NHEADS), 256, 0, stream>>>(ws_q, ws_k, ws_v, ws_attn);

    // dense GEMM: 128x256 tile -> grid 16x16 = 256 blocks (full CU coverage)
    gemm_fc_kernel<256, 2, false><<<dim3(HID / 256, S_LEN / 128), 512, 0, stream>>>(
        ws_attn, ws_wd, b_dense, out, S_LEN, HID, HID);
}

// Round 8
// 511.083 us; speedup vs baseline: 1.1269x; 1.0192x over previous
//
#include <hip/hip_runtime.h>

#define S_LEN   2048
#define HID     4096
#define NHEADS  32
#define NKVH    8
#define HDIM    128
#define NQKV    6144          // NKV*(QPK+2)*HD = 8*6*128
#define ATT_SCALE (1.0f/128.0f)

typedef unsigned short u16;
typedef __attribute__((ext_vector_type(8))) __bf16 bf16x8;
typedef __attribute__((ext_vector_type(4))) float  f32x4;

__device__ __forceinline__ u16 f2bf(float f) {
    union { float f; unsigned u; } x; x.f = f;
    unsigned u = x.u;
    u += 0x7fffu + ((u >> 16) & 1u);   // round-to-nearest-even
    return (u16)(u >> 16);
}
__device__ __forceinline__ float bf2f(u16 v) {
    union { unsigned u; float f; } x; x.u = ((unsigned)v) << 16; return x.f;
}

// ---------------- fp32 -> bf16 conversion ----------------
__global__ __launch_bounds__(256) void cvt_bf16_kernel(const float* __restrict__ in,
                                                       u16* __restrict__ out, int n4) {
    int stride = gridDim.x * blockDim.x;
    for (int i = blockIdx.x * blockDim.x + threadIdx.x; i < n4; i += stride) {
        float4 v = *(const float4*)(in + (size_t)i * 4);
        ushort4 o = make_ushort4(f2bf(v.x), f2bf(v.y), f2bf(v.z), f2bf(v.w));
        *(ushort4*)(out + (size_t)i * 4) = o;
    }
}

// ---------------- full-coverage GEMM: 128 x BN tile, counted-vmcnt schedule ----------------
// (unchanged from round-7 passing config; see its header comment for the ledger)
#define GFENCE() asm volatile("" ::: "memory")
#define GSBAR()  do { GFENCE(); __builtin_amdgcn_s_barrier(); GFENCE(); } while (0)

template <int BN_, int NB_, bool OUT_BF16>
__global__ __launch_bounds__(512, 2) void gemm_fc_kernel(
    const u16* __restrict__ A,   // M x K  bf16
    const u16* __restrict__ B,   // N x K  bf16
    const float* __restrict__ bias,
    void* __restrict__ Cout,     // M x N
    int M, int N, int K)
{
    constexpr int LB = BN_ / 128;          // gload_lds per B-half per wave
    constexpr int VM = 2 + LB;             // counted-wait value (5 or 4)
    __shared__ u16 lds[16384 + 2 * BN_ * 64];

    const int tid  = threadIdx.x;
    const int wid  = tid >> 6;        // 0..7
    const int lane = tid & 63;
    const int ln   = lane & 15;
    const int quad = lane >> 4;
    const int wr   = wid >> 2;        // 0..1 (M split)
    const int wc   = wid & 3;         // 0..3 (N split)
    const int tileM = blockIdx.y * 128;
    const int tileN = blockIdx.x * BN_;

    f32x4 acc[2][NB_][4];             // [b][n][m]
    #pragma unroll
    for (int b = 0; b < 2; b++)
        #pragma unroll
        for (int n = 0; n < NB_; n++)
            #pragma unroll
            for (int m = 0; m < 4; m++) {
                f32x4 z = {0.f, 0.f, 0.f, 0.f};
                acc[b][n][m] = z;
            }

    const int srho = lane >> 3;                       // row within 8-row group
    const int scol = (((lane & 7) ^ srho) << 3);      // pre-swizzled source chunk

    auto gload = [&](const u16* src, u16* dst) {
        __builtin_amdgcn_global_load_lds(
            (const __attribute__((address_space(1))) void*)src,
            (__attribute__((address_space(3))) void*)dst, 16, 0, 0);
    };
    // A unit: 128 rows, 2 loads/wave
    auto stage_A = [&](int kk, int bb) {
        const int base = bb * 8192;
        #pragma unroll
        for (int s = 0; s < 2; s++) {
            const int rho0 = s * 64 + wid * 8;        // wave-uniform, ≡0 mod 8
            const int rho  = rho0 + srho;
            const u16* src = A + (size_t)(tileM + rho) * K + (size_t)kk * 64 + scol;
            gload(src, &lds[base + rho0 * 64]);
        }
    };
    // B half h: BN/2 rows, LB loads/wave
    auto stage_Bh = [&](int h, int kk, int bb) {
        const int base = 16384 + bb * (BN_ * 64) + h * ((BN_ / 2) * 64);
        #pragma unroll
        for (int s = 0; s < LB; s++) {
            const int rho0 = s * 64 + wid * 8;
            const int rho  = rho0 + srho;
            const u16* src = B + (size_t)(tileN + h * (BN_ / 2) + rho) * K
                               + (size_t)kk * 64 + scol;
            gload(src, &lds[base + rho0 * 64]);
        }
    };

#define WAIT_VM()                                                                   \
    do {                                                                            \
        if constexpr (VM == 5) asm volatile("s_waitcnt vmcnt(5)" ::: "memory");     \
        else                   asm volatile("s_waitcnt vmcnt(4)" ::: "memory");     \
    } while (0)

#define READ_A()                                                                    \
    do {                                                                            \
        _Pragma("unroll")                                                           \
        for (int m = 0; m < 4; m++) {                                               \
            const int ra = wr * 64 + m * 16 + ln;                                   \
            const int ab = buf * 8192 + ra * 64;                                    \
            const int rx = ra & 7;                                                  \
            af[m][0] = *(const bf16x8*)(&lds[ab + ((quad ^ rx) << 3)]);             \
            af[m][1] = *(const bf16x8*)(&lds[ab + (((4 + quad) ^ rx) << 3)]);       \
        }                                                                           \
    } while (0)

// streamed: one bfr pair live at a time (no in-loop spill risk)
#define MFMA_B(b_)                                                                  \
    do {                                                                            \
        __builtin_amdgcn_s_setprio(1);                                              \
        _Pragma("unroll")                                                           \
        for (int n = 0; n < NB_; n++) {                                             \
            const int rb = (b_) * (BN_ / 2) + wc * (NB_ * 16) + n * 16 + ln;        \
            const int bb = 16384 + buf * (BN_ * 64) + rb * 64;                      \
            const int rx = rb & 7;                                                  \
            bf16x8 b0 = *(const bf16x8*)(&lds[bb + ((quad ^ rx) << 3)]);            \
            bf16x8 b1 = *(const bf16x8*)(&lds[bb + (((4 + quad) ^ rx) << 3)]);      \
            _Pragma("unroll")                                                       \
            for (int m = 0; m < 4; m++) {                                           \
                acc[b_][n][m] = __builtin_amdgcn_mfma_f32_16x16x32_bf16(            \
                    af[m][0], b0, acc[b_][n][m], 0, 0, 0);                          \
                acc[b_][n][m] = __builtin_amdgcn_mfma_f32_16x16x32_bf16(            \
                    af[m][1], b1, acc[b_][n][m], 0, 0, 0);                          \
            }                                                                       \
        }                                                                           \
        __builtin_amdgcn_s_setprio(0);                                              \
    } while (0)

    const int nIter = K / 64;

    // prologue: tile 0 -> buf0, order A, B0, B1 (order matters for the ledger)
    stage_A(0, 0); stage_Bh(0, 0, 0); stage_Bh(1, 0, 0);

    bf16x8 af[4][2];

    for (int t = 0; t < nIter; t++) {
        const int buf = t & 1;
        const int bn  = buf ^ 1;
        const int kn  = (t + 1 == nIter) ? 0 : t + 1;   // final-iter dummy keeps counts uniform

        // ---- P0: b=0 needs A(t) + B0(t) ----
        stage_A(kn, bn);
        WAIT_VM();             // outstanding 2*2+2*LB -> forces A(t), B0(t)
        GSBAR();
        READ_A();
        MFMA_B(0);

        // ---- P1: b=1 needs B1(t); af reused ----
        stage_Bh(0, kn, bn);
        WAIT_VM();             // outstanding LB+2+LB -> forces B1(t)
        GSBAR();
        MFMA_B(1);
        stage_Bh(1, kn, bn);

        asm volatile("s_waitcnt lgkmcnt(0)" ::: "memory");  // all buf reads complete
        GSBAR();                                            // before t+1 DMAs into buf
    }

    // CRITICAL drain: final-iter dummy stages still in flight; LDS-DMA landing
    // after s_endpgm faults / corrupts the next workgroup's LDS.
    asm volatile("s_waitcnt vmcnt(0)" ::: "memory");

#undef WAIT_VM
#undef READ_A
#undef MFMA_B

    // epilogue
    #pragma unroll
    for (int b = 0; b < 2; b++)
        #pragma unroll
        for (int n = 0; n < NB_; n++) {
            const int col = tileN + b * (BN_ / 2) + wc * (NB_ * 16) + n * 16 + ln;
            const float bv = bias[col];
            #pragma unroll
            for (int m = 0; m < 4; m++) {
                #pragma unroll
                for (int r = 0; r < 4; r++) {
                    const int row = tileM + wr * 64 + m * 16 + quad * 4 + r;
                    float v = acc[b][n][m][r] + bv;
                    if (OUT_BF16)
                        ((u16*)Cout)[(size_t)row * N + col] = f2bf(v);
                    else
                        ((float*)Cout)[(size_t)row * N + col] = v;
                }
            }
        }
}

// ---------------- RoPE + split qkv (bf16 in, bf16 out) ----------------
// v-copy removed: V is handled by vtrans_kernel. grid y = NHEADS + NKVH = 40.
__global__ __launch_bounds__(128) void rope_split_kernel(
    const u16* __restrict__ qkv, const int* __restrict__ positions,
    u16* __restrict__ qb_o, u16* __restrict__ kb_o)
{
    const int d   = threadIdx.x;     // 0..127
    const int pos = blockIdx.x;      // 0..S-1
    const int hy  = blockIdx.y;      // 0..39
    const float p = (float)positions[pos];

    const u16* src;
    u16* dst;
    if (hy < NHEADS) {                        // q head
        int kv = hy >> 2, qi = hy & 3;
        src = qkv + (size_t)pos * NQKV + (kv * 6 + qi) * HDIM;
        dst = qb_o + ((size_t)hy * S_LEN + pos) * HDIM;
    } else {                                  // k head
        int kv = hy - NHEADS;
        src = qkv + (size_t)pos * NQKV + (kv * 6 + 4) * HDIM;
        dst = kb_o + ((size_t)kv * S_LEN + pos) * HDIM;
    }
    int d2 = d & 63;
    float inv = expf(-(float)d2 * (13.815510557964274f / 64.0f)); // 1e6^(-d2/64)
    float fr = p * inv;
    float s, c;
    sincosf(fr, &s, &c);
    float x1 = bf2f(src[d2]);
    float x2 = bf2f(src[d2 + 64]);
    float o = (d < 64) ? (x1 * c - x2 * s) : (x2 * c + x1 * s);
    dst[d] = f2bf(o);
}

// ---------------- one-shot V transpose: qkv -> VT (NKV, HD, S) ----------------
// Hoists the per-tile V transpose out of attention (was 32 scalar ds_writes
// per thread per kb-tile, ~13k tiles; now paid once over 256 blocks).
__global__ __launch_bounds__(256) void vtrans_kernel(
    const u16* __restrict__ qkv,   // (S, NQKV)
    u16* __restrict__ VT)          // (NKV, HDIM, S)
{
    __shared__ u16 T[64][HDIM + 8];
    const int s0 = blockIdx.x * 64;
    const int kv = blockIdx.y;
    const int tid = threadIdx.x;
    // coalesced read: 64 pos x 128 dim
    #pragma unroll
    for (int p = 0; p < 4; p++) {
        int pos = p * 16 + (tid >> 4);
        int d   = (tid & 15) * 8;
        *(uint4*)&T[pos][d] =
            *(const uint4*)(qkv + (size_t)(s0 + pos) * NQKV + (kv * 6 + 5) * HDIM + d);
    }
    __syncthreads();
    // coalesced write: 128 dim rows x 64 pos
    #pragma unroll
    for (int p = 0; p < 4; p++) {
        int d  = p * 32 + (tid >> 3);
        int sc = (tid & 7) * 8;
        u16 tmp[8];
        #pragma unroll
        for (int j = 0; j < 8; j++) tmp[j] = T[sc + j][d];
        *(uint4*)(VT + ((size_t)kv * HDIM + d) * S_LEN + s0 + sc) = *(uint4*)tmp;
    }
}

// ---------------- blocksparse flash attention ----------------
// grid (S/64, NH); block 256 (4 waves). Wave w owns query rows w*16..w*16+15.
// Round-8: (1) V pre-transposed globally -> Vt staged via 4 global_load_lds
// per wave (16B chunks contiguous along keys in VT), same 3-bit XOR involution
// as K; read side unchanged (pattern bank-verified clean in the GEMM).
// (2) T13 defer-max: skip alpha-rescale unless any row grew > 8 (wave-uniform
// __any branch; first tile always rescales since m0 = -1e30; P <= e^8, f32
// accum safe). LDS 40960 B -> 4 blocks/CU; qb reversed; setprio on MFMA.
__global__ __launch_bounds__(256, 4) void attn_bs_kernel(
    const u16* __restrict__ Q,   // (NH, S, HD) bf16
    const u16* __restrict__ K,   // (NKV, S, HD)
    const u16* __restrict__ V,   // (NKV, HD, S)  TRANSPOSED
    u16* __restrict__ O)         // (S, NH*HD) bf16
{
    __shared__ u16 Ks[64 * 128];      // 16 KB, swizzled
    __shared__ u16 Vt[128 * 64];      // 16 KB, V^T, swizzled
    __shared__ u16 Ps[4][16 * 64];    // 8 KB, per-wave P, swizzled

    const int qb = (int)gridDim.x - 1 - (int)blockIdx.x;   // heavy blocks first
    const int h  = blockIdx.y;
    const int kv = h >> 2;
    const int tid  = threadIdx.x;
    const int w    = tid >> 6;
    const int lane = tid & 63;
    const int ln   = lane & 15;
    const int quad = lane >> 4;

    bf16x8 aq[4];
    {
        const u16* Qg = Q + ((size_t)h * S_LEN + qb * 64 + w * 16 + ln) * HDIM + quad * 8;
        #pragma unroll
        for (int ks = 0; ks < 4; ks++)
            aq[ks] = *(const bf16x8*)(Qg + ks * 32);
    }

    f32x4 oacc[8];
    #pragma unroll
    for (int n = 0; n < 8; n++) { f32x4 z = {0.f,0.f,0.f,0.f}; oacc[n] = z; }
    float mrow[4] = {-1e30f, -1e30f, -1e30f, -1e30f};
    float lrow[4] = {0.f, 0.f, 0.f, 0.f};

    for (int kb = 0; kb <= qb; kb++) {
        bool sel = (qb - kb < 16) || (((kb + h + 1) & 7) == 0);
        if (!sel) continue;

        __syncthreads();   // previous iteration's LDS reads complete

        const u16* Kg  = K + ((size_t)kv * S_LEN + kb * 64) * HDIM;
        const u16* VTg = V + (size_t)kv * HDIM * S_LEN + kb * 64;

        // K stage: 4 gload_lds/wave, 4 rows each; pre-swizzled source
        #pragma unroll
        for (int p = 0; p < 4; p++) {
            int r0  = w * 16 + p * 4;
            int row = r0 + (lane >> 4);
            const u16* src = Kg + (size_t)row * HDIM + (((lane & 15) ^ (row & 7)) << 3);
            __builtin_amdgcn_global_load_lds(
                (const __attribute__((address_space(1))) void*)src,
                (__attribute__((address_space(3))) void*)&Ks[r0 * 128], 16, 0, 0);
        }
        // Vt stage: 4 gload_lds/wave, 8 dim-rows each; 16B contiguous along keys
        #pragma unroll
        for (int p = 0; p < 4; p++) {
            int r0  = w * 32 + p * 8;
            int row = r0 + (lane >> 3);
            int c   = (lane & 7) ^ (row & 7);
            const u16* src = VTg + (size_t)row * S_LEN + c * 8;
            __builtin_amdgcn_global_load_lds(
                (const __attribute__((address_space(1))) void*)src,
                (__attribute__((address_space(3))) void*)&Vt[r0 * 64], 16, 0, 0);
        }
        __syncthreads();   // drains vmcnt -> K, Vt resident

        // S = Q K^T  (wave's 16 rows x 64 keys)
        f32x4 sacc[4];
        #pragma unroll
        for (int jj = 0; jj < 4; jj++) { f32x4 z = {0.f,0.f,0.f,0.f}; sacc[jj] = z; }
        __builtin_amdgcn_s_setprio(1);
        #pragma unroll
        for (int ks = 0; ks < 4; ks++) {
            #pragma unroll
            for (int jj = 0; jj < 4; jj++) {
                bf16x8 bk = *(const bf16x8*)(
                    &Ks[(jj * 16 + ln) * 128 + (((ks * 4 + quad) ^ (ln & 7)) << 3)]);
                sacc[jj] = __builtin_amdgcn_mfma_f32_16x16x32_bf16(aq[ks], bk, sacc[jj], 0, 0, 0);
            }
        }
        __builtin_amdgcn_s_setprio(0);

        // scale + diagonal mask; per-row max; T13 defer-max
        const bool diag = (kb == qb);
        float pv[4][4], mxr[4];
        bool grow = false;
        #pragma unroll
        for (int r = 0; r < 4; r++) {
            const int qrow = w * 16 + quad * 4 + r;
            float mx = -1e30f;
            #pragma unroll
            for (int jj = 0; jj < 4; jj++) {
                float s = sacc[jj][r] * ATT_SCALE;
                if (diag && (jj * 16 + ln) > qrow) s = -1e30f;
                pv[r][jj] = s;
                mx = fmaxf(mx, s);
            }
            #pragma unroll
            for (int off = 1; off < 16; off <<= 1)
                mx = fmaxf(mx, __shfl_xor(mx, off, 64));
            mxr[r] = mx;
            grow |= (mx > mrow[r] + 8.0f);
        }
        if (__any(grow)) {           // wave-uniform rescale path
            #pragma unroll
            for (int r = 0; r < 4; r++) {
                float mnew  = fmaxf(mrow[r], mxr[r]);
                float alpha = __expf(mrow[r] - mnew);
                lrow[r] *= alpha;
                mrow[r]  = mnew;
                #pragma unroll
                for (int n = 0; n < 8; n++) oacc[n][r] *= alpha;
            }
        }
        #pragma unroll
        for (int r = 0; r < 4; r++) {
            float sum = 0.f;
            #pragma unroll
            for (int jj = 0; jj < 4; jj++) {
                float pe = __expf(pv[r][jj] - mrow[r]);
                pv[r][jj] = pe;
                sum += pe;
            }
            #pragma unroll
            for (int off = 1; off < 16; off <<= 1)
                sum += __shfl_xor(sum, off, 64);
            lrow[r] += sum;
            const int prow = quad * 4 + r;
            #pragma unroll
            for (int jj = 0; jj < 4; jj++)
                Ps[w][prow * 64 + (((jj * 2 + (ln >> 3)) ^ (prow & 7)) << 3) + (ln & 7)]
                    = f2bf(pv[r][jj]);
        }
        // no barrier: Ps[w] is written and read only by wave w (in-order DS pipe)

        // O += P V
        __builtin_amdgcn_s_setprio(1);
        #pragma unroll
        for (int kk = 0; kk < 2; kk++) {
            bf16x8 ap = *(const bf16x8*)(
                &Ps[w][ln * 64 + (((kk * 4 + quad) ^ (ln & 7)) << 3)]);
            #pragma unroll
            for (int n = 0; n < 8; n++) {
                bf16x8 bv = *(const bf16x8*)(
                    &Vt[(n * 16 + ln) * 64 + (((kk * 4 + quad) ^ (ln & 7)) << 3)]);
                oacc[n] = __builtin_amdgcn_mfma_f32_16x16x32_bf16(ap, bv, oacc[n], 0, 0, 0);
            }
        }
        __builtin_amdgcn_s_setprio(0);
    }

    #pragma unroll
    for (int n = 0; n < 8; n++) {
        #pragma unroll
        for (int r = 0; r < 4; r++) {
            int row = w * 16 + quad * 4 + r;
            int pos = qb * 64 + row;
            float o = oacc[n][r] / lrow[r];
            O[(size_t)pos * (NHEADS * HDIM) + h * HDIM + n * 16 + ln] = f2bf(o);
        }
    }
}

// ---------------- launch ----------------
extern "C" void kernel_launch(void* const* d_in, const int* in_sizes, int n_in,
                              void* d_out, int out_size, void* d_ws, size_t ws_size,
                              hipStream_t stream) {
    const int*   positions = (const int*)d_in[0];
    const float* hidden    = (const float*)d_in[1];
    const float* w_qkv     = (const float*)d_in[2];
    const float* b_qkv     = (const float*)d_in[3];
    const float* w_dense   = (const float*)d_in[4];
    const float* b_dense   = (const float*)d_in[5];
    float* out = (float*)d_out;

    char* ws = (char*)d_ws;
    u16* ws_h    = (u16*)(ws);                    // 2048*4096*2   = 16,777,216
    u16* ws_wqkv = (u16*)(ws + 16777216);         // 6144*4096*2  = 50,331,648
    u16* ws_wd   = (u16*)(ws + 67108864);         // 4096*4096*2  = 33,554,432
    u16* ws_qkv  = (u16*)(ws + 100663296);        // 2048*6144*2  = 25,165,824 (bf16)
    u16* ws_q    = (u16*)(ws + 125829120);        // 32*2048*128*2= 16,777,216
    u16* ws_k    = (u16*)(ws + 142606336);        // 8*2048*128*2 =  4,194,304
    u16* ws_v    = (u16*)(ws + 146800640);        // VT (NKV,HD,S) =  4,194,304
    u16* ws_attn = (u16*)(ws + 150994944);        // 2048*4096*2  = 16,777,216

    cvt_bf16_kernel<<<1024, 256, 0, stream>>>(hidden,  ws_h,    (S_LEN * HID) / 4);
    cvt_bf16_kernel<<<2048, 256, 0, stream>>>(w_qkv,   ws_wqkv, (NQKV * HID) / 4);
    cvt_bf16_kernel<<<2048, 256, 0, stream>>>(w_dense, ws_wd,   (HID * HID) / 4);

    // QKV GEMM: 128x384 tile -> grid 16x16 = 256 blocks (full CU coverage)
    gemm_fc_kernel<384, 3, true><<<dim3(NQKV / 384, S_LEN / 128), 512, 0, stream>>>(
        ws_h, ws_wqkv, b_qkv, ws_qkv, S_LEN, NQKV, HID);

    rope_split_kernel<<<dim3(S_LEN, NHEADS + NKVH), 128, 0, stream>>>(
        ws_qkv, positions, ws_q, ws_k);

    vtrans_kernel<<<dim3(S_LEN / 64, NKVH), 256, 0, stream>>>(ws_qkv, ws_v);

    attn_bs_kernel<<<dim3(S_LEN / 64, NHEADS), 256, 0, stream>>>(ws_q, ws_k, ws_v, ws_attn);

    // dense GEMM: 128x256 tile -> grid 16x16 = 256 blocks (full CU coverage)
    gemm_fc_kernel<256, 2, false><<<dim3(HID / 256, S_LEN / 128), 512, 0, stream>>>(
        ws_attn, ws_wd, b_dense, out, S_LEN, HID, HID);
}